// Round 6
// baseline (194.292 us; speedup 1.0000x reference)
//
#include <hip/hip_runtime.h>
#include <stdint.h>

typedef __bf16 bf16_t;
typedef __bf16 bf16x8 __attribute__((ext_vector_type(8)));
typedef float f32x4 __attribute__((ext_vector_type(4)));

#define S_LEN 2048
#define D_MODEL 1024
#define NH 16
#define DKV 64
#define BATCH 2

// 0.125 (1/sqrt(64)) * log2(e): Q pre-scale so softmax runs in exp2 domain.
#define QSCALE 0.1803368801111204f

__device__ __forceinline__ uint16_t f2bfu(float f) {
    union { float f; uint32_t u; } c; c.f = f;
    return (uint16_t)((c.u + 0x7fffu + ((c.u >> 16) & 1u)) >> 16);
}
__device__ __forceinline__ bf16_t f2bf(float f) {
    union { uint16_t s; bf16_t b; } o; o.s = f2bfu(f);
    return o.b;
}
// truncation pack via v_perm: result = (lo>>16) | (hi & 0xFFFF0000)
__device__ __forceinline__ uint32_t pack2t(float lo, float hi) {
    union { float f; uint32_t u; } a, b; a.f = lo; b.f = hi;
    return __builtin_amdgcn_perm(b.u, a.u, 0x07060302);
}
// rounding pack (RTNE, matches f2bf) — two bf16 in one u32
__device__ __forceinline__ uint32_t pack2r(float lo, float hi) {
    union { float f; uint32_t u; } a, b; a.f = lo; b.f = hi;
    uint32_t alo = a.u + 0x7fffu + ((a.u >> 16) & 1u);
    uint32_t bhi = b.u + 0x7fffu + ((b.u >> 16) & 1u);
    return __builtin_amdgcn_perm(bhi, alo, 0x07060302);
}
// native 2^x (trans pipe, 1 instr; avoids any OCML wrapper overhead)
__device__ __forceinline__ float exp2_native(float x) {
    float r;
    asm("v_exp_f32 %0, %1" : "=v"(r) : "v"(x));
    return r;
}
// async global->LDS 16B DMA (dst = wave-uniform base + lane*16)
__device__ __forceinline__ void gld_lds16(const bf16_t* g, bf16_t* l) {
    __builtin_amdgcn_global_load_lds(
        (const __attribute__((address_space(1))) void*)g,
        (__attribute__((address_space(3))) void*)l, 16, 0, 0);
}

// ---------- merged prep: fp32->bf16 convert (x) + weight transpose, one launch ----------
__global__ __launch_bounds__(256) void k_prep(
    const float* __restrict__ x, bf16_t* __restrict__ xb,
    const float* __restrict__ Wq, const float* __restrict__ Wk,
    const float* __restrict__ Wv, const float* __restrict__ Wo,
    bf16_t* __restrict__ WqkvT, bf16_t* __restrict__ WoT) {
    __shared__ float tile[64][65];
    int bid = blockIdx.x;
    if (bid < 4096) {
        int i = (bid * 256 + threadIdx.x) * 4;
        float4 v = *(const float4*)(x + i);
        xb[i + 0] = f2bf(v.x);
        xb[i + 1] = f2bf(v.y);
        xb[i + 2] = f2bf(v.z);
        xb[i + 3] = f2bf(v.w);
        return;
    }
    int b2 = bid - 4096;
    int k0 = (b2 & 15) * 64;
    int n0 = (b2 >> 4) * 64;
    const float* W; bf16_t* WT; int np, nw;
    if (n0 < 3072) {
        W = (n0 < 1024) ? Wq : (n0 < 2048) ? Wk : Wv;
        np = n0 & 1023; WT = WqkvT; nw = n0;
    } else {
        W = Wo; np = n0 - 3072; WT = WoT; nw = n0 - 3072;
    }
    int tx = threadIdx.x & 63, ty = threadIdx.x >> 6;
    #pragma unroll
    for (int r = ty; r < 64; r += 4)
        tile[r][tx] = W[(size_t)(k0 + r) * 1024 + np + tx];
    __syncthreads();
    #pragma unroll
    for (int r = ty; r < 64; r += 4)
        WT[(size_t)(nw + r) * 1024 + k0 + tx] = f2bf(tile[tx][r]);
}

// ---------- QKV GEMM (verified R5): swapped Q/K epilogue, V LDS-transpose ----------
#define BM 128
#define BN 128
#define BKK 64

__global__ __launch_bounds__(256) void k_gemm_qkv(
    const bf16_t* __restrict__ A, const bf16_t* __restrict__ BT, int K,
    const float* __restrict__ bias0, const float* __restrict__ bias1,
    const float* __restrict__ bias2,
    bf16_t* __restrict__ outQ, bf16_t* __restrict__ outK, bf16_t* __restrict__ outVt) {
    __shared__ __align__(16) bf16_t smem[BM * BKK + BN * BKK];  // As | Bs ; epilogue overlay
    bf16_t* const As = smem;
    bf16_t* const Bs = smem + BM * BKK;
    int m0 = blockIdx.x * BM;
    int n0 = blockIdx.y * BN;
    int t = threadIdx.x;
    int wid = t >> 6, lane = t & 63, l15 = lane & 15, quad = lane >> 4;
    int wr = (wid >> 1) * 64, wc = (wid & 1) * 64;
    int srow = t >> 3;
    int schunk = (t & 7) ^ (srow & 7);
    int sldst = (t & 7) * 8;
    const f32x4 fzero = {0.f, 0.f, 0.f, 0.f};
    f32x4 acc[4][4];
    #pragma unroll
    for (int i = 0; i < 4; i++)
        #pragma unroll
        for (int j = 0; j < 4; j++) acc[i][j] = fzero;

    int secb = n0 >> 10;  // block-uniform: 0=Q, 1=K, 2=V
    int r7 = l15 & 7;
    for (int k0 = 0; k0 < K; k0 += BKK) {
        #pragma unroll
        for (int p = 0; p < 4; p++) {
            int r = p * 32 + srow;
            gld_lds16(&A[(size_t)(m0 + r) * K + k0 + schunk * 8], &As[r * 64 + sldst]);
            gld_lds16(&BT[(size_t)(n0 + r) * K + k0 + schunk * 8], &Bs[r * 64 + sldst]);
        }
        __syncthreads();
        if (secb == 2) {
            #pragma unroll
            for (int kk = 0; kk < BKK; kk += 32) {
                int g = quad + (kk >> 3);
                int col = ((g ^ r7) << 3);
                bf16x8 af[4], bfr[4];
                #pragma unroll
                for (int mt = 0; mt < 4; mt++)
                    af[mt] = *(const bf16x8*)&As[(wr + mt * 16 + l15) * 64 + col];
                #pragma unroll
                for (int nt = 0; nt < 4; nt++)
                    bfr[nt] = *(const bf16x8*)&Bs[(wc + nt * 16 + l15) * 64 + col];
                #pragma unroll
                for (int mt = 0; mt < 4; mt++)
                    #pragma unroll
                    for (int nt = 0; nt < 4; nt++)
                        acc[mt][nt] = __builtin_amdgcn_mfma_f32_16x16x32_bf16(
                            af[mt], bfr[nt], acc[mt][nt], 0, 0, 0);
            }
        } else {
            #pragma unroll
            for (int kk = 0; kk < BKK; kk += 32) {
                int g = quad + (kk >> 3);
                int col = ((g ^ r7) << 3);
                bf16x8 af[4], bfr[4];
                #pragma unroll
                for (int mt = 0; mt < 4; mt++)
                    af[mt] = *(const bf16x8*)&As[(wr + mt * 16 + l15) * 64 + col];
                #pragma unroll
                for (int nt = 0; nt < 4; nt++)
                    bfr[nt] = *(const bf16x8*)&Bs[(wc + nt * 16 + l15) * 64 + col];
                #pragma unroll
                for (int i = 0; i < 4; i++)
                    #pragma unroll
                    for (int j = 0; j < 4; j++)
                        acc[i][j] = __builtin_amdgcn_mfma_f32_16x16x32_bf16(
                            bfr[i], af[j], acc[i][j], 0, 0, 0);
            }
        }
        __syncthreads();
    }

    if (secb == 2) {
        bf16_t* const Ct = smem;  // 128*128*2B = 32KB, exactly As+Bs
        int nbase = n0 & 1023;
        #pragma unroll
        for (int mt = 0; mt < 4; mt++) {
            #pragma unroll
            for (int nt = 0; nt < 4; nt++) {
                int dl = wc + nt * 16 + l15;
                float bv = bias2[nbase + dl];
                int sl = wr + mt * 16 + quad * 4;  // multiple of 4
                uint2 pk;
                pk.x = pack2t(acc[mt][nt][0] + bv, acc[mt][nt][1] + bv);
                pk.y = pack2t(acc[mt][nt][2] + bv, acc[mt][nt][3] + bv);
                int c4 = (sl >> 2) ^ ((dl & 7) << 1);
                *(uint2*)&Ct[dl * 128 + c4 * 4] = pk;
            }
        }
        __syncthreads();
        int b = m0 >> 11, sb = m0 & 2047;
        #pragma unroll
        for (int rr = 0; rr < 8; rr++) {
            int row = rr * 16 + (t >> 4);      // d-local 0..127
            int s8 = t & 15;                   // 16B chunk along s
            int c4 = (s8 * 2) ^ ((row & 7) << 1);
            uint4 vv = *(const uint4*)&Ct[row * 128 + c4 * 4];
            int nn = nbase + row;
            int h = nn >> 6, d = nn & 63;
            *(uint4*)&outVt[(((size_t)(b * NH + h)) * DKV + d) * S_LEN + sb + s8 * 8] = vv;
        }
        return;
    }

    {
        const float* bias = (secb == 0) ? bias0 : bias1;
        bf16_t* outP = (secb == 0) ? outQ : outK;
        float scale = (secb == 0) ? QSCALE : 1.0f;
        #pragma unroll
        for (int i = 0; i < 4; i++) {
            #pragma unroll
            for (int j = 0; j < 4; j++) {
                int nn = (n0 + wc + i * 16 + quad * 4) & 1023;  // multiple of 4
                float4 bv = *(const float4*)&bias[nn];
                int gr = m0 + wr + j * 16 + l15;
                int b = gr >> 11, s = gr & 2047;
                int h = nn >> 6, d0 = nn & 63;
                float v0 = (acc[i][j][0] + bv.x) * scale;
                float v1 = (acc[i][j][1] + bv.y) * scale;
                float v2 = (acc[i][j][2] + bv.z) * scale;
                float v3 = (acc[i][j][3] + bv.w) * scale;
                uint2 pk;
                pk.x = pack2r(v0, v1);
                pk.y = pack2r(v2, v3);
                *(uint2*)&outP[(((size_t)(b * NH + h)) * S_LEN + s) * DKV + d0] = pk;
            }
        }
    }
}

// ---------- out GEMM (verified R5): swapped operands -> float4 stores ----------
__global__ __launch_bounds__(256) void k_gemm_out(
    const bf16_t* __restrict__ A, const bf16_t* __restrict__ BT, int N, int K,
    const float* __restrict__ bias, float* __restrict__ outF) {
    __shared__ __align__(16) bf16_t As[128 * 64];
    __shared__ __align__(16) bf16_t Bs[64 * 64];
    int m0 = blockIdx.x * 128;
    int n0 = blockIdx.y * 64;
    int t = threadIdx.x;
    int wid = t >> 6, lane = t & 63, l15 = lane & 15, quad = lane >> 4;
    int wr = wid * 32;
    int srow = t >> 3;
    int schunk = (t & 7) ^ (srow & 7);
    int sldst = (t & 7) * 8;
    const f32x4 fzero = {0.f, 0.f, 0.f, 0.f};
    f32x4 acc[4][2];  // [n-tile][m-tile] (swapped orientation)
    #pragma unroll
    for (int i = 0; i < 4; i++)
        #pragma unroll
        for (int j = 0; j < 2; j++) acc[i][j] = fzero;

    int r7 = l15 & 7;
    for (int k0 = 0; k0 < K; k0 += 64) {
        #pragma unroll
        for (int p = 0; p < 4; p++) {
            int r = p * 32 + srow;
            gld_lds16(&A[(size_t)(m0 + r) * K + k0 + schunk * 8], &As[r * 64 + sldst]);
        }
        #pragma unroll
        for (int p = 0; p < 2; p++) {
            int r = p * 32 + srow;
            gld_lds16(&BT[(size_t)(n0 + r) * K + k0 + schunk * 8], &Bs[r * 64 + sldst]);
        }
        __syncthreads();
        #pragma unroll
        for (int kk = 0; kk < 64; kk += 32) {
            int g = quad + (kk >> 3);
            int col = ((g ^ r7) << 3);
            bf16x8 af[2], bfr[4];
            #pragma unroll
            for (int j = 0; j < 2; j++)
                af[j] = *(const bf16x8*)&As[(wr + j * 16 + l15) * 64 + col];
            #pragma unroll
            for (int i = 0; i < 4; i++)
                bfr[i] = *(const bf16x8*)&Bs[(i * 16 + l15) * 64 + col];
            #pragma unroll
            for (int i = 0; i < 4; i++)
                #pragma unroll
                for (int j = 0; j < 2; j++)
                    acc[i][j] = __builtin_amdgcn_mfma_f32_16x16x32_bf16(
                        bfr[i], af[j], acc[i][j], 0, 0, 0);
        }
        __syncthreads();
    }

    #pragma unroll
    for (int i = 0; i < 4; i++) {
        #pragma unroll
        for (int j = 0; j < 2; j++) {
            int nc = n0 + i * 16 + quad * 4;   // multiple of 4
            float4 bv = *(const float4*)&bias[nc];
            int mr = m0 + wr + j * 16 + l15;
            float4 o;
            o.x = acc[i][j][0] + bv.x;
            o.y = acc[i][j][1] + bv.y;
            o.z = acc[i][j][2] + bv.z;
            o.w = acc[i][j][3] + bv.w;
            *(float4*)&outF[(size_t)mr * N + nc] = o;
        }
    }
}

// ---------- flash attention v12: QBLK=128, K/V fragments amortized over 2 q-groups ----------
// Theory (R6): the v11 kernel was LDS-read/staging-bound: each wave read the full
// K-tile (8 b128) + V-tile (8 b128) for only 16 q-rows (~280cy LDS vs ~90cy MFMA
// per tile). v12: each wave owns 32 q (2 x 16-row groups); af/vf are loaded ONCE
// per tile and reused for both groups -> 20 b128 per 2x work (1.8x less LDS
// traffic/FLOP); staging + barriers per unit work halved. Same verified TILE
// skeleton: double-buffered KV=64, stage-before-compute, one barrier/tile,
// mask-gate, native exp2, setprio. Grid 512 (2/CU), LDS 48KB, lb(256,2).
// Causal: ktmax = 2qt+1; per-group wave-uniform active/diag guards; last tile
// leaves waves 0,1 idle at the barrier (structurally fine, barrier is outside).
__global__ __launch_bounds__(256, 2) void k_attn12(
    const bf16_t* __restrict__ Q, const bf16_t* __restrict__ Kg,
    const bf16_t* __restrict__ Vt, const unsigned char* __restrict__ mask,
    bf16_t* __restrict__ O) {
    __shared__ __align__(16) bf16_t Ks0[64 * 64];
    __shared__ __align__(16) bf16_t Ks1[64 * 64];
    __shared__ __align__(16) bf16_t Vs0[64 * 64];
    __shared__ __align__(16) bf16_t Vs1[64 * 64];
    __shared__ __align__(16) bf16_t Ps[128 * 64];  // per-wave 32 rows (2 groups)

    int bid = blockIdx.x;
    int bh = bid & 31;
    int u = bid >> 5;                       // 0..15
    int qt = (u < 8) ? (15 - u) : (u - 8);  // round 1 gets heavy tiles; CU pairs sum 15
    int b = bh >> 4, h = bh & 15;
    int t = threadIdx.x;
    int w = t >> 6, lane = t & 63, l15 = lane & 15, quad = lane >> 4;
    int r7 = l15 & 7;

    // wave-uniform: any padded position in this batch row?
    bool maskany;
    {
        const uint2* mrow = (const uint2*)&mask[b * S_LEN];
        uint2 m0 = mrow[lane], m1 = mrow[lane + 64];
        uint2 m2 = mrow[lane + 128], m3 = mrow[lane + 192];
        uint32_t mo = (m0.x | m0.y) | (m1.x | m1.y) | (m2.x | m2.y) | (m3.x | m3.y);
        maskany = __any(mo != 0);
    }

    // Q fragments for both groups straight from global
    const bf16_t* Q0 = Q + ((size_t)bh * S_LEN + qt * 128 + w * 32 + l15) * DKV;
    bf16x8 qf[2][2];
    qf[0][0] = *(const bf16x8*)&Q0[quad * 8];
    qf[0][1] = *(const bf16x8*)&Q0[32 + quad * 8];
    qf[1][0] = *(const bf16x8*)&Q0[16 * DKV + quad * 8];
    qf[1][1] = *(const bf16x8*)&Q0[16 * DKV + 32 + quad * 8];

    const bf16_t* Kbh = Kg + (size_t)bh * S_LEN * DKV;   // [s][64]
    const bf16_t* Vbh = Vt + (size_t)bh * DKV * S_LEN;   // [64][2048]

    const f32x4 fzero = {0.f, 0.f, 0.f, 0.f};
    f32x4 oacc[2][4];
    f32x4 lacc[2] = {fzero, fzero};
    #pragma unroll
    for (int g = 0; g < 2; g++)
        #pragma unroll
        for (int nt = 0; nt < 4; nt++) oacc[g][nt] = fzero;

    const bf16_t one_b = (bf16_t)1.0f;
    const bf16x8 onesf = {one_b, one_b, one_b, one_b, one_b, one_b, one_b, one_b};

    int qmin0 = qt * 128 + w * 32;  // group g: qmin = qmin0 + 16g

    // staging lane constants ([64][64] tile)
    int sr = t >> 3;
    int sc = (t & 7) ^ (sr & 7);
    int sl = (t & 7) * 8;

    // prologue: stage tile 0 into buffer 0
    #pragma unroll
    for (int p = 0; p < 2; p++) {
        int r = p * 32 + sr;
        gld_lds16(&Kbh[(size_t)r * DKV + sc * 8], &Ks0[r * 64 + sl]);
        gld_lds16(&Vbh[(size_t)r * S_LEN + sc * 8], &Vs0[r * 64 + sl]);
    }
    __syncthreads();

    int ktmax = 2 * qt + 1;

    auto TILE = [&](const bf16_t* __restrict__ Kr, const bf16_t* __restrict__ Vr,
                    bf16_t* __restrict__ Kw, bf16_t* __restrict__ Vw, int kt) {
        if (kt < ktmax) {
            int kb2 = (kt + 1) * 64;
            #pragma unroll
            for (int p = 0; p < 2; p++) {
                int r = p * 32 + sr;
                gld_lds16(&Kbh[(size_t)(kb2 + r) * DKV + sc * 8], &Kw[r * 64 + sl]);
                gld_lds16(&Vbh[(size_t)r * S_LEN + kb2 + sc * 8], &Vw[r * 64 + sl]);
            }
        }
        int kbase = kt * 64;
        bool act0 = (kbase <= qmin0 + 15);   // wave-uniform
        bool act1 = (kbase <= qmin0 + 31);   // act0 => act1

        if (act1) {
            f32x4 sacc[2][4];
            #pragma unroll
            for (int g = 0; g < 2; g++)
                #pragma unroll
                for (int mt = 0; mt < 4; mt++) sacc[g][mt] = fzero;

            // S^T: row k = mt*16+quad*4+r, col q = l15 (per group)
            #pragma unroll
            for (int kk = 0; kk < 64; kk += 32) {
                int col = (((quad + (kk >> 3)) ^ r7) << 3);
                bf16x8 af[4];
                #pragma unroll
                for (int mt = 0; mt < 4; mt++)
                    af[mt] = *(const bf16x8*)&Kr[(mt * 16 + l15) * 64 + col];
                __builtin_amdgcn_s_setprio(1);
                if (act0) {
                    #pragma unroll
                    for (int mt = 0; mt < 4; mt++)
                        sacc[0][mt] = __builtin_amdgcn_mfma_f32_16x16x32_bf16(
                            af[mt], qf[0][kk ? 1 : 0], sacc[0][mt], 0, 0, 0);
                }
                #pragma unroll
                for (int mt = 0; mt < 4; mt++)
                    sacc[1][mt] = __builtin_amdgcn_mfma_f32_16x16x32_bf16(
                        af[mt], qf[1][kk ? 1 : 0], sacc[1][mt], 0, 0, 0);
                __builtin_amdgcn_s_setprio(0);
            }

            if (maskany) {
                #pragma unroll
                for (int mt = 0; mt < 4; mt++) {
                    uint32_t mb = *(const uint32_t*)&mask[b * S_LEN + kbase + mt * 16 + quad * 4];
                    #pragma unroll
                    for (int r = 0; r < 4; r++) {
                        float pen = (float)((mb >> (8 * r)) & 0xffu) * -1e30f;
                        sacc[0][mt][r] += pen;
                        sacc[1][mt][r] += pen;
                    }
                }
            }
            // causal diag per group (wave-uniform conditions)
            #pragma unroll
            for (int g = 0; g < 2; g++) {
                int qming = qmin0 + 16 * g;
                if (kbase + 63 > qming) {
                    int qg = qming + l15;
                    #pragma unroll
                    for (int mt = 0; mt < 4; mt++) {
                        int kgb = kbase + mt * 16 + quad * 4;
                        #pragma unroll
                        for (int r = 0; r < 4; r++)
                            if (kgb + r > qg) sacc[g][mt][r] = -1e30f;
                    }
                }
            }
            // p = exp2(s); store both groups to Ps (rows w*32+g*16+l15)
            #pragma unroll
            for (int g = 0; g < 2; g++) {
                if (g == 0 && !act0) continue;
                int prow = (w * 32 + g * 16 + l15) * 64;
                #pragma unroll
                for (int mt = 0; mt < 4; mt++) {
                    uint2 pk;
                    pk.x = pack2t(exp2_native(sacc[g][mt][0]), exp2_native(sacc[g][mt][1]));
                    pk.y = pack2t(exp2_native(sacc[g][mt][2]), exp2_native(sacc[g][mt][3]));
                    int pc = (mt * 2 + (quad >> 1)) ^ r7;
                    *(uint2*)&Ps[prow + pc * 8 + (quad & 1) * 4] = pk;
                }
            }

            // O += P V; l += P * ones — vf loaded once, used by both groups
            #pragma unroll
            for (int kk = 0; kk < 64; kk += 32) {
                int vcol = (((quad + (kk >> 3)) ^ r7) << 3);
                bf16x8 vf[4];
                #pragma unroll
                for (int nt = 0; nt < 4; nt++)
                    vf[nt] = *(const bf16x8*)&Vr[(nt * 16 + l15) * 64 + vcol];
                bf16x8 pf0, pf1;
                if (act0) pf0 = *(const bf16x8*)&Ps[(w * 32 + l15) * 64 + vcol];
                pf1 = *(const bf16x8*)&Ps[(w * 32 + 16 + l15) * 64 + vcol];
                __builtin_amdgcn_s_setprio(1);
                if (act0) {
                    #pragma unroll
                    for (int nt = 0; nt < 4; nt++)
                        oacc[0][nt] = __builtin_amdgcn_mfma_f32_16x16x32_bf16(
                            pf0, vf[nt], oacc[0][nt], 0, 0, 0);
                    lacc[0] = __builtin_amdgcn_mfma_f32_16x16x32_bf16(pf0, onesf, lacc[0], 0, 0, 0);
                }
                #pragma unroll
                for (int nt = 0; nt < 4; nt++)
                    oacc[1][nt] = __builtin_amdgcn_mfma_f32_16x16x32_bf16(
                        pf1, vf[nt], oacc[1][nt], 0, 0, 0);
                lacc[1] = __builtin_amdgcn_mfma_f32_16x16x32_bf16(pf1, onesf, lacc[1], 0, 0, 0);
                __builtin_amdgcn_s_setprio(0);
            }
        }

        if (kt < ktmax) __syncthreads();  // block-uniform
    };

    for (int kt = 0; kt <= ktmax; kt += 2) {
        TILE(Ks0, Vs0, Ks1, Vs1, kt);
        TILE(Ks1, Vs1, Ks0, Vs0, kt + 1);  // ktmax is odd -> always valid
    }

    #pragma unroll
    for (int g = 0; g < 2; g++) {
        #pragma unroll
        for (int r = 0; r < 4; r++) {
            float l = lacc[g][r];
            float invl = l > 0.f ? 1.f / l : 0.f;
            int q = qt * 128 + w * 32 + g * 16 + quad * 4 + r;
            #pragma unroll
            for (int nt = 0; nt < 4; nt++) {
                int d = nt * 16 + l15;
                O[((size_t)b * S_LEN + q) * D_MODEL + h * DKV + d] = f2bf(oacc[g][nt][r] * invl);
            }
        }
    }
}

extern "C" void kernel_launch(void* const* d_in, const int* in_sizes, int n_in,
                              void* d_out, int out_size, void* d_ws, size_t ws_size,
                              hipStream_t stream) {
    const float* x = (const float*)d_in[0];
    const unsigned char* mask = (const unsigned char*)d_in[1];
    const float* Wq = (const float*)d_in[2];
    const float* bq = (const float*)d_in[3];
    const float* Wk = (const float*)d_in[4];
    const float* bk = (const float*)d_in[5];
    const float* Wv = (const float*)d_in[6];
    const float* bv = (const float*)d_in[7];
    const float* Wo = (const float*)d_in[8];
    const float* bo = (const float*)d_in[9];
    float* out = (float*)d_out;

    char* ws = (char*)d_ws;
    const size_t MB = 1024 * 1024;
    // Max ws footprint: 48 MB.
    bf16_t* xb    = (bf16_t*)(ws + 0 * MB);   // 8 MB
    bf16_t* WqkvT = (bf16_t*)(ws + 8 * MB);   // 6 MB
    bf16_t* WoT   = (bf16_t*)(ws + 14 * MB);  // 2 MB
    bf16_t* Qb    = (bf16_t*)(ws + 16 * MB);  // 8 MB [bh][s][64], pre-scaled QSCALE
    bf16_t* Kb    = (bf16_t*)(ws + 24 * MB);  // 8 MB [bh][s][64]
    bf16_t* Vtb   = (bf16_t*)(ws + 32 * MB);  // 8 MB V^T [bh][64][2048]
    bf16_t* AOb   = (bf16_t*)(ws + 40 * MB);  // 8 MB attn out [4096,1024]

    k_prep<<<dim3(4096 + 1024), dim3(256), 0, stream>>>(
        x, xb, Wq, Wk, Wv, Wo, WqkvT, WoT);
    k_gemm_qkv<<<dim3(32, 24), dim3(256), 0, stream>>>(
        xb, WqkvT, 1024, bq, bk, bv, Qb, Kb, Vtb);
    k_attn12<<<dim3(512), dim3(256), 0, stream>>>(Qb, Kb, Vtb, mask, AOb);
    k_gemm_out<<<dim3(32, 16), dim3(256), 0, stream>>>(
        AOb, WoT, 1024, 1024, bo, out);
}

// Round 7
// 179.908 us; speedup vs baseline: 1.0800x; 1.0800x over previous
//
#include <hip/hip_runtime.h>
#include <stdint.h>

typedef __bf16 bf16_t;
typedef __bf16 bf16x8 __attribute__((ext_vector_type(8)));
typedef float f32x4 __attribute__((ext_vector_type(4)));

#define S_LEN 2048
#define D_MODEL 1024
#define NH 16
#define DKV 64
#define BATCH 2

// 0.125 (1/sqrt(64)) * log2(e): Q pre-scale so softmax runs in exp2 domain.
#define QSCALE 0.1803368801111204f

__device__ __forceinline__ uint16_t f2bfu(float f) {
    union { float f; uint32_t u; } c; c.f = f;
    return (uint16_t)((c.u + 0x7fffu + ((c.u >> 16) & 1u)) >> 16);
}
__device__ __forceinline__ bf16_t f2bf(float f) {
    union { uint16_t s; bf16_t b; } o; o.s = f2bfu(f);
    return o.b;
}
// truncation pack via v_perm: result = (lo>>16) | (hi & 0xFFFF0000)
__device__ __forceinline__ uint32_t pack2t(float lo, float hi) {
    union { float f; uint32_t u; } a, b; a.f = lo; b.f = hi;
    return __builtin_amdgcn_perm(b.u, a.u, 0x07060302);
}
// rounding pack (RTNE, matches f2bf) — two bf16 in one u32
__device__ __forceinline__ uint32_t pack2r(float lo, float hi) {
    union { float f; uint32_t u; } a, b; a.f = lo; b.f = hi;
    uint32_t alo = a.u + 0x7fffu + ((a.u >> 16) & 1u);
    uint32_t bhi = b.u + 0x7fffu + ((b.u >> 16) & 1u);
    return __builtin_amdgcn_perm(bhi, alo, 0x07060302);
}
// native 2^x (trans pipe, 1 instr)
__device__ __forceinline__ float exp2_native(float x) {
    float r;
    asm("v_exp_f32 %0, %1" : "=v"(r) : "v"(x));
    return r;
}
// async global->LDS 16B DMA (dst = wave-uniform base + lane*16)
__device__ __forceinline__ void gld_lds16(const bf16_t* g, bf16_t* l) {
    __builtin_amdgcn_global_load_lds(
        (const __attribute__((address_space(1))) void*)g,
        (__attribute__((address_space(3))) void*)l, 16, 0, 0);
}

// ---------- merged prep: fp32->bf16 convert (x) + weight transpose, one launch ----------
__global__ __launch_bounds__(256) void k_prep(
    const float* __restrict__ x, bf16_t* __restrict__ xb,
    const float* __restrict__ Wq, const float* __restrict__ Wk,
    const float* __restrict__ Wv, const float* __restrict__ Wo,
    bf16_t* __restrict__ WqkvT, bf16_t* __restrict__ WoT) {
    __shared__ float tile[64][65];
    int bid = blockIdx.x;
    if (bid < 4096) {
        int i = (bid * 256 + threadIdx.x) * 4;
        float4 v = *(const float4*)(x + i);
        xb[i + 0] = f2bf(v.x);
        xb[i + 1] = f2bf(v.y);
        xb[i + 2] = f2bf(v.z);
        xb[i + 3] = f2bf(v.w);
        return;
    }
    int b2 = bid - 4096;
    int k0 = (b2 & 15) * 64;
    int n0 = (b2 >> 4) * 64;
    const float* W; bf16_t* WT; int np, nw;
    if (n0 < 3072) {
        W = (n0 < 1024) ? Wq : (n0 < 2048) ? Wk : Wv;
        np = n0 & 1023; WT = WqkvT; nw = n0;
    } else {
        W = Wo; np = n0 - 3072; WT = WoT; nw = n0 - 3072;
    }
    int tx = threadIdx.x & 63, ty = threadIdx.x >> 6;
    #pragma unroll
    for (int r = ty; r < 64; r += 4)
        tile[r][tx] = W[(size_t)(k0 + r) * 1024 + np + tx];
    __syncthreads();
    #pragma unroll
    for (int r = ty; r < 64; r += 4)
        WT[(size_t)(nw + r) * 1024 + k0 + tx] = f2bf(tile[tx][r]);
}

// ---------- QKV GEMM v2: BKK=32 double-buffered, stage-before-compute ----------
// R7: same total LDS (4 x 8KB = 32KB, occupancy unchanged) but the m97-style
// "stage -> barrier(vmcnt drain) -> compute" is restructured to the in-problem
// proven pattern (attn v8->v10, -18%): STAGE(next buf) issued BEFORE compute(cur),
// one barrier per 32-K step -> the barrier's vmcnt drain only pays the residual
// DMA latency after a full compute phase. Epilogues identical to R5 (verified):
// Q/K swapped-operand direct stores; V LDS-transpose + coalesced Vt writes.
#define BM 128
#define BN 128

__global__ __launch_bounds__(256) void k_gemm_qkv(
    const bf16_t* __restrict__ A, const bf16_t* __restrict__ BT, int K,
    const float* __restrict__ bias0, const float* __restrict__ bias1,
    const float* __restrict__ bias2,
    bf16_t* __restrict__ outQ, bf16_t* __restrict__ outK, bf16_t* __restrict__ outVt) {
    // 4 x [128][32] bf16 = 32KB; epilogue overlays the same 32KB as Ct[128][128]
    __shared__ __align__(16) bf16_t smem[4 * 128 * 32];
    bf16_t* const As0 = smem;
    bf16_t* const As1 = smem + 128 * 32;
    bf16_t* const Bs0 = smem + 2 * 128 * 32;
    bf16_t* const Bs1 = smem + 3 * 128 * 32;
    int m0 = blockIdx.x * BM;
    int n0 = blockIdx.y * BN;
    int t = threadIdx.x;
    int wid = t >> 6, lane = t & 63, l15 = lane & 15, quad = lane >> 4;
    int wr = (wid >> 1) * 64, wc = (wid & 1) * 64;
    // staging constants for [128][32] tiles: 2 calls/thread/matrix
    int sr = t >> 2;                 // row 0..63 (+64 second call)
    int sc = (t & 3) ^ (sr & 3);     // XOR-swizzled source chunk (4 x 16B/row)
    int sl = (t & 3) * 8;            // linear dst chunk
    const f32x4 fzero = {0.f, 0.f, 0.f, 0.f};
    f32x4 acc[4][4];
    #pragma unroll
    for (int i = 0; i < 4; i++)
        #pragma unroll
        for (int j = 0; j < 4; j++) acc[i][j] = fzero;

    int secb = n0 >> 10;  // block-uniform: 0=Q, 1=K, 2=V
    int r3 = l15 & 3;
    int colA = (quad ^ r3) << 3;  // lane's k-chunk (quad) at XOR'd physical slot

    auto STAGE = [&](bf16_t* __restrict__ Ad, bf16_t* __restrict__ Bd, int k0) {
        #pragma unroll
        for (int p = 0; p < 2; p++) {
            int r = p * 64 + sr;
            gld_lds16(&A[(size_t)(m0 + r) * K + k0 + sc * 8], &Ad[r * 32 + sl]);
            gld_lds16(&BT[(size_t)(n0 + r) * K + k0 + sc * 8], &Bd[r * 32 + sl]);
        }
    };

    auto STEP = [&](const bf16_t* __restrict__ Ar, const bf16_t* __restrict__ Br,
                    bf16_t* __restrict__ Aw, bf16_t* __restrict__ Bw, int i) {
        if (i + 1 < 32) STAGE(Aw, Bw, (i + 1) * 32);
        bf16x8 af[4], bfr[4];
        #pragma unroll
        for (int mt = 0; mt < 4; mt++)
            af[mt] = *(const bf16x8*)&Ar[(wr + mt * 16 + l15) * 32 + colA];
        #pragma unroll
        for (int nt = 0; nt < 4; nt++)
            bfr[nt] = *(const bf16x8*)&Br[(wc + nt * 16 + l15) * 32 + colA];
        __builtin_amdgcn_s_setprio(1);
        if (secb == 2) {
            #pragma unroll
            for (int mt = 0; mt < 4; mt++)
                #pragma unroll
                for (int nt = 0; nt < 4; nt++)
                    acc[mt][nt] = __builtin_amdgcn_mfma_f32_16x16x32_bf16(
                        af[mt], bfr[nt], acc[mt][nt], 0, 0, 0);
        } else {
            #pragma unroll
            for (int i2 = 0; i2 < 4; i2++)
                #pragma unroll
                for (int j = 0; j < 4; j++)
                    acc[i2][j] = __builtin_amdgcn_mfma_f32_16x16x32_bf16(
                        bfr[i2], af[j], acc[i2][j], 0, 0, 0);
        }
        __builtin_amdgcn_s_setprio(0);
        if (i + 1 < 32) __syncthreads();
    };

    STAGE(As0, Bs0, 0);
    __syncthreads();
    for (int i = 0; i < 32; i += 2) {
        STEP(As0, Bs0, As1, Bs1, i);
        STEP(As1, Bs1, As0, Bs0, i + 1);
    }

    if (secb == 2) {
        __syncthreads();          // all waves done with As/Bs before overlay
        bf16_t* const Ct = smem;  // 128*128*2B = 32KB overlay
        int nbase = n0 & 1023;
        #pragma unroll
        for (int mt = 0; mt < 4; mt++) {
            #pragma unroll
            for (int nt = 0; nt < 4; nt++) {
                int dl = wc + nt * 16 + l15;
                float bv = bias2[nbase + dl];
                int sl2 = wr + mt * 16 + quad * 4;  // multiple of 4
                uint2 pk;
                pk.x = pack2t(acc[mt][nt][0] + bv, acc[mt][nt][1] + bv);
                pk.y = pack2t(acc[mt][nt][2] + bv, acc[mt][nt][3] + bv);
                int c4 = (sl2 >> 2) ^ ((dl & 7) << 1);
                *(uint2*)&Ct[dl * 128 + c4 * 4] = pk;
            }
        }
        __syncthreads();
        int b = m0 >> 11, sb = m0 & 2047;
        #pragma unroll
        for (int rr = 0; rr < 8; rr++) {
            int row = rr * 16 + (t >> 4);      // d-local 0..127
            int s8 = t & 15;                   // 16B chunk along s
            int c4 = (s8 * 2) ^ ((row & 7) << 1);
            uint4 vv = *(const uint4*)&Ct[row * 128 + c4 * 4];
            int nn = nbase + row;
            int h = nn >> 6, d = nn & 63;
            *(uint4*)&outVt[(((size_t)(b * NH + h)) * DKV + d) * S_LEN + sb + s8 * 8] = vv;
        }
        return;
    }

    {
        const float* bias = (secb == 0) ? bias0 : bias1;
        bf16_t* outP = (secb == 0) ? outQ : outK;
        float scale = (secb == 0) ? QSCALE : 1.0f;
        #pragma unroll
        for (int i = 0; i < 4; i++) {
            #pragma unroll
            for (int j = 0; j < 4; j++) {
                int nn = (n0 + wc + i * 16 + quad * 4) & 1023;  // multiple of 4
                float4 bv = *(const float4*)&bias[nn];
                int gr = m0 + wr + j * 16 + l15;
                int b = gr >> 11, s = gr & 2047;
                int h = nn >> 6, d0 = nn & 63;
                float v0 = (acc[i][j][0] + bv.x) * scale;
                float v1 = (acc[i][j][1] + bv.y) * scale;
                float v2 = (acc[i][j][2] + bv.z) * scale;
                float v3 = (acc[i][j][3] + bv.w) * scale;
                uint2 pk;
                pk.x = pack2r(v0, v1);
                pk.y = pack2r(v2, v3);
                *(uint2*)&outP[(((size_t)(b * NH + h)) * S_LEN + s) * DKV + d0] = pk;
            }
        }
    }
}

// ---------- out GEMM (verified R5): swapped operands -> float4 stores ----------
__global__ __launch_bounds__(256) void k_gemm_out(
    const bf16_t* __restrict__ A, const bf16_t* __restrict__ BT, int N, int K,
    const float* __restrict__ bias, float* __restrict__ outF) {
    __shared__ __align__(16) bf16_t As[128 * 64];
    __shared__ __align__(16) bf16_t Bs[64 * 64];
    int m0 = blockIdx.x * 128;
    int n0 = blockIdx.y * 64;
    int t = threadIdx.x;
    int wid = t >> 6, lane = t & 63, l15 = lane & 15, quad = lane >> 4;
    int wr = wid * 32;
    int srow = t >> 3;
    int schunk = (t & 7) ^ (srow & 7);
    int sldst = (t & 7) * 8;
    const f32x4 fzero = {0.f, 0.f, 0.f, 0.f};
    f32x4 acc[4][2];  // [n-tile][m-tile] (swapped orientation)
    #pragma unroll
    for (int i = 0; i < 4; i++)
        #pragma unroll
        for (int j = 0; j < 2; j++) acc[i][j] = fzero;

    int r7 = l15 & 7;
    for (int k0 = 0; k0 < K; k0 += 64) {
        #pragma unroll
        for (int p = 0; p < 4; p++) {
            int r = p * 32 + srow;
            gld_lds16(&A[(size_t)(m0 + r) * K + k0 + schunk * 8], &As[r * 64 + sldst]);
        }
        #pragma unroll
        for (int p = 0; p < 2; p++) {
            int r = p * 32 + srow;
            gld_lds16(&BT[(size_t)(n0 + r) * K + k0 + schunk * 8], &Bs[r * 64 + sldst]);
        }
        __syncthreads();
        #pragma unroll
        for (int kk = 0; kk < 64; kk += 32) {
            int g = quad + (kk >> 3);
            int col = ((g ^ r7) << 3);
            bf16x8 af[2], bfr[4];
            #pragma unroll
            for (int j = 0; j < 2; j++)
                af[j] = *(const bf16x8*)&As[(wr + j * 16 + l15) * 64 + col];
            #pragma unroll
            for (int i = 0; i < 4; i++)
                bfr[i] = *(const bf16x8*)&Bs[(i * 16 + l15) * 64 + col];
            #pragma unroll
            for (int i = 0; i < 4; i++)
                #pragma unroll
                for (int j = 0; j < 2; j++)
                    acc[i][j] = __builtin_amdgcn_mfma_f32_16x16x32_bf16(
                        bfr[i], af[j], acc[i][j], 0, 0, 0);
        }
        __syncthreads();
    }

    #pragma unroll
    for (int i = 0; i < 4; i++) {
        #pragma unroll
        for (int j = 0; j < 2; j++) {
            int nc = n0 + i * 16 + quad * 4;   // multiple of 4
            float4 bv = *(const float4*)&bias[nc];
            int mr = m0 + wr + j * 16 + l15;
            float4 o;
            o.x = acc[i][j][0] + bv.x;
            o.y = acc[i][j][1] + bv.y;
            o.z = acc[i][j][2] + bv.z;
            o.w = acc[i][j][3] + bv.w;
            *(float4*)&outF[(size_t)mr * N + nc] = o;
        }
    }
}

// ---------- flash attention v11 (verified R4/R5, reverted from regressed v12) ----------
// Double-buffered KV=64 tiles, STAGE(next) before compute(cur), one barrier per
// tile; pad-mask gated behind wave-uniform scan; Q direct from global; setprio(1)
// around MFMA clusters; native exp2. LDS 40KB -> 4 blocks/CU.
__global__ __launch_bounds__(256, 4) void k_attn11(
    const bf16_t* __restrict__ Q, const bf16_t* __restrict__ Kg,
    const bf16_t* __restrict__ Vt, const unsigned char* __restrict__ mask,
    bf16_t* __restrict__ O) {
    __shared__ __align__(16) bf16_t Ks0[64 * 64];
    __shared__ __align__(16) bf16_t Ks1[64 * 64];
    __shared__ __align__(16) bf16_t Vs0[64 * 64];
    __shared__ __align__(16) bf16_t Vs1[64 * 64];
    __shared__ __align__(16) bf16_t Ps[64 * 64];  // per-wave 16-row P buffer

    int bid = blockIdx.x;
    int bh = bid & 31;
    int u = bid >> 5;
    int a = u & 7, g2 = u >> 3;
    int qt = (g2 == 0) ? 31 - a : (g2 == 1) ? a : (g2 == 2) ? 23 - a : 8 + a;
    int b = bh >> 4, h = bh & 15;
    int t = threadIdx.x;
    int w = t >> 6, lane = t & 63, l15 = lane & 15, quad = lane >> 4;
    int r7 = l15 & 7;

    // wave-uniform: any padded position in this batch row?
    bool maskany;
    {
        const uint2* mrow = (const uint2*)&mask[b * S_LEN];
        uint2 m0 = mrow[lane], m1 = mrow[lane + 64];
        uint2 m2 = mrow[lane + 128], m3 = mrow[lane + 192];
        uint32_t mo = (m0.x | m0.y) | (m1.x | m1.y) | (m2.x | m2.y) | (m3.x | m3.y);
        maskany = __any(mo != 0);
    }

    // Q fragments straight from global (row = this lane's q, 2 x 16B chunks)
    const bf16_t* Qrow = Q + ((size_t)bh * S_LEN + qt * 64 + w * 16 + l15) * DKV;
    bf16x8 qf0 = *(const bf16x8*)&Qrow[quad * 8];
    bf16x8 qf1 = *(const bf16x8*)&Qrow[32 + quad * 8];

    const bf16_t* Kbh = Kg + (size_t)bh * S_LEN * DKV;   // [s][64]
    const bf16_t* Vbh = Vt + (size_t)bh * DKV * S_LEN;   // [64][2048]

    const f32x4 fzero = {0.f, 0.f, 0.f, 0.f};
    f32x4 oacc[4];
    f32x4 lacc = fzero;
    #pragma unroll
    for (int nt = 0; nt < 4; nt++) oacc[nt] = fzero;

    const bf16_t one_b = (bf16_t)1.0f;
    const bf16x8 onesf = {one_b, one_b, one_b, one_b, one_b, one_b, one_b, one_b};

    int qg = qt * 64 + w * 16 + l15;  // lane's q column in S^T
    int qmin = qt * 64 + w * 16;

    // staging lane constants ([64][64] tile, 8 chunks/row)
    int sr = t >> 3;
    int sc = (t & 7) ^ (sr & 7);
    int sl = (t & 7) * 8;

    // prologue: stage tile 0 into buffer 0
    #pragma unroll
    for (int p = 0; p < 2; p++) {
        int r = p * 32 + sr;
        gld_lds16(&Kbh[(size_t)r * DKV + sc * 8], &Ks0[r * 64 + sl]);
        gld_lds16(&Vbh[(size_t)r * S_LEN + sc * 8], &Vs0[r * 64 + sl]);
    }
    __syncthreads();

    auto TILE = [&](const bf16_t* __restrict__ Kr, const bf16_t* __restrict__ Vr,
                    bf16_t* __restrict__ Kw, bf16_t* __restrict__ Vw, int kt) {
        if (kt < qt) {
            int kb2 = (kt + 1) * 64;
            #pragma unroll
            for (int p = 0; p < 2; p++) {
                int r = p * 32 + sr;
                gld_lds16(&Kbh[(size_t)(kb2 + r) * DKV + sc * 8], &Kw[r * 64 + sl]);
                gld_lds16(&Vbh[(size_t)r * S_LEN + kb2 + sc * 8], &Vw[r * 64 + sl]);
            }
        }
        int kbase = kt * 64;

        // S^T subtile: row k = mt*16+quad*4+r, col q = l15
        f32x4 sacc[4];
        #pragma unroll
        for (int mt = 0; mt < 4; mt++) sacc[mt] = fzero;
        #pragma unroll
        for (int kk = 0; kk < 64; kk += 32) {
            bf16x8 qf = kk ? qf1 : qf0;
            int col = (((quad + (kk >> 3)) ^ r7) << 3);
            bf16x8 af[4];
            #pragma unroll
            for (int mt = 0; mt < 4; mt++)
                af[mt] = *(const bf16x8*)&Kr[(mt * 16 + l15) * 64 + col];
            __builtin_amdgcn_s_setprio(1);
            #pragma unroll
            for (int mt = 0; mt < 4; mt++)
                sacc[mt] = __builtin_amdgcn_mfma_f32_16x16x32_bf16(af[mt], qf, sacc[mt], 0, 0, 0);
            __builtin_amdgcn_s_setprio(0);
        }

        if (maskany) {  // rare path: apply pad mask from global bytes
            #pragma unroll
            for (int mt = 0; mt < 4; mt++) {
                uint32_t mb = *(const uint32_t*)&mask[b * S_LEN + kbase + mt * 16 + quad * 4];
                #pragma unroll
                for (int r = 0; r < 4; r++)
                    sacc[mt][r] += (float)((mb >> (8 * r)) & 0xffu) * -1e30f;
            }
        }
        if (kt == qt) {  // causal mask only on the diagonal tile
            #pragma unroll
            for (int mt = 0; mt < 4; mt++) {
                int kgb = kbase + mt * 16 + quad * 4;
                #pragma unroll
                for (int r = 0; r < 4; r++)
                    if (kgb + r > qg) sacc[mt][r] = -1e30f;
            }
        }
        // p = exp2(s)
        #pragma unroll
        for (int mt = 0; mt < 4; mt++) {
            uint2 pk;
            pk.x = pack2t(exp2_native(sacc[mt][0]), exp2_native(sacc[mt][1]));
            pk.y = pack2t(exp2_native(sacc[mt][2]), exp2_native(sacc[mt][3]));
            int pc = (mt * 2 + (quad >> 1)) ^ r7;
            *(uint2*)&Ps[(w * 16 + l15) * 64 + pc * 8 + (quad & 1) * 4] = pk;
        }

        // O += P V; l += P * ones
        #pragma unroll
        for (int kk = 0; kk < 64; kk += 32) {
            int vcol = (((quad + (kk >> 3)) ^ r7) << 3);
            bf16x8 pf = *(const bf16x8*)&Ps[(w * 16 + l15) * 64 + vcol];
            bf16x8 vf[4];
            #pragma unroll
            for (int nt = 0; nt < 4; nt++)
                vf[nt] = *(const bf16x8*)&Vr[(nt * 16 + l15) * 64 + vcol];
            __builtin_amdgcn_s_setprio(1);
            #pragma unroll
            for (int nt = 0; nt < 4; nt++)
                oacc[nt] = __builtin_amdgcn_mfma_f32_16x16x32_bf16(pf, vf[nt], oacc[nt], 0, 0, 0);
            lacc = __builtin_amdgcn_mfma_f32_16x16x32_bf16(pf, onesf, lacc, 0, 0, 0);
            __builtin_amdgcn_s_setprio(0);
        }

        if (kt < qt) __syncthreads();  // drains stage DMA; block-uniform condition
    };

    for (int kt = 0; kt <= qt; kt += 2) {
        TILE(Ks0, Vs0, Ks1, Vs1, kt);
        if (kt + 1 <= qt) TILE(Ks1, Vs1, Ks0, Vs0, kt + 1);
    }

    #pragma unroll
    for (int r = 0; r < 4; r++) {
        float l = lacc[r];
        float invl = l > 0.f ? 1.f / l : 0.f;
        int q = qt * 64 + w * 16 + quad * 4 + r;
        #pragma unroll
        for (int nt = 0; nt < 4; nt++) {
            int d = nt * 16 + l15;
            O[((size_t)b * S_LEN + q) * D_MODEL + h * DKV + d] = f2bf(oacc[nt][r] * invl);
        }
    }
}

extern "C" void kernel_launch(void* const* d_in, const int* in_sizes, int n_in,
                              void* d_out, int out_size, void* d_ws, size_t ws_size,
                              hipStream_t stream) {
    const float* x = (const float*)d_in[0];
    const unsigned char* mask = (const unsigned char*)d_in[1];
    const float* Wq = (const float*)d_in[2];
    const float* bq = (const float*)d_in[3];
    const float* Wk = (const float*)d_in[4];
    const float* bk = (const float*)d_in[5];
    const float* Wv = (const float*)d_in[6];
    const float* bv = (const float*)d_in[7];
    const float* Wo = (const float*)d_in[8];
    const float* bo = (const float*)d_in[9];
    float* out = (float*)d_out;

    char* ws = (char*)d_ws;
    const size_t MB = 1024 * 1024;
    // Max ws footprint: 48 MB.
    bf16_t* xb    = (bf16_t*)(ws + 0 * MB);   // 8 MB
    bf16_t* WqkvT = (bf16_t*)(ws + 8 * MB);   // 6 MB
    bf16_t* WoT   = (bf16_t*)(ws + 14 * MB);  // 2 MB
    bf16_t* Qb    = (bf16_t*)(ws + 16 * MB);  // 8 MB [bh][s][64], pre-scaled QSCALE
    bf16_t* Kb    = (bf16_t*)(ws + 24 * MB);  // 8 MB [bh][s][64]
    bf16_t* Vtb   = (bf16_t*)(ws + 32 * MB);  // 8 MB V^T [bh][64][2048]
    bf16_t* AOb   = (bf16_t*)(ws + 40 * MB);  // 8 MB attn out [4096,1024]

    k_prep<<<dim3(4096 + 1024), dim3(256), 0, stream>>>(
        x, xb, Wq, Wk, Wv, Wo, WqkvT, WoT);
    k_gemm_qkv<<<dim3(32, 24), dim3(256), 0, stream>>>(
        xb, WqkvT, 1024, bq, bk, bv, Qb, Kb, Vtb);
    k_attn11<<<dim3(1024), dim3(256), 0, stream>>>(Qb, Kb, Vtb, mask, AOb);
    k_gemm_out<<<dim3(32, 16), dim3(256), 0, stream>>>(
        AOb, WoT, 1024, 1024, bo, out);
}

// Round 8
// 176.512 us; speedup vs baseline: 1.1007x; 1.0192x over previous
//
#include <hip/hip_runtime.h>
#include <stdint.h>

typedef __bf16 bf16_t;
typedef __bf16 bf16x8 __attribute__((ext_vector_type(8)));
typedef float f32x4 __attribute__((ext_vector_type(4)));

#define S_LEN 2048
#define D_MODEL 1024
#define NH 16
#define DKV 64
#define BATCH 2

// 0.125 (1/sqrt(64)) * log2(e): Q pre-scale so softmax runs in exp2 domain.
#define QSCALE 0.1803368801111204f

__device__ __forceinline__ uint16_t f2bfu(float f) {
    union { float f; uint32_t u; } c; c.f = f;
    return (uint16_t)((c.u + 0x7fffu + ((c.u >> 16) & 1u)) >> 16);
}
__device__ __forceinline__ bf16_t f2bf(float f) {
    union { uint16_t s; bf16_t b; } o; o.s = f2bfu(f);
    return o.b;
}
// truncation pack via v_perm: result = (lo>>16) | (hi & 0xFFFF0000)
__device__ __forceinline__ uint32_t pack2t(float lo, float hi) {
    union { float f; uint32_t u; } a, b; a.f = lo; b.f = hi;
    return __builtin_amdgcn_perm(b.u, a.u, 0x07060302);
}
// rounding pack (RTNE, matches f2bf) — two bf16 in one u32
__device__ __forceinline__ uint32_t pack2r(float lo, float hi) {
    union { float f; uint32_t u; } a, b; a.f = lo; b.f = hi;
    uint32_t alo = a.u + 0x7fffu + ((a.u >> 16) & 1u);
    uint32_t bhi = b.u + 0x7fffu + ((b.u >> 16) & 1u);
    return __builtin_amdgcn_perm(bhi, alo, 0x07060302);
}
// native 2^x (trans pipe, 1 instr)
__device__ __forceinline__ float exp2_native(float x) {
    float r;
    asm("v_exp_f32 %0, %1" : "=v"(r) : "v"(x));
    return r;
}
// async global->LDS 16B DMA (dst = wave-uniform base + lane*16)
__device__ __forceinline__ void gld_lds16(const bf16_t* g, bf16_t* l) {
    __builtin_amdgcn_global_load_lds(
        (const __attribute__((address_space(1))) void*)g,
        (__attribute__((address_space(3))) void*)l, 16, 0, 0);
}

// ---------- merged prep: fp32->bf16 convert (x) + weight transpose, one launch ----------
__global__ __launch_bounds__(256) void k_prep(
    const float* __restrict__ x, bf16_t* __restrict__ xb,
    const float* __restrict__ Wq, const float* __restrict__ Wk,
    const float* __restrict__ Wv, const float* __restrict__ Wo,
    bf16_t* __restrict__ WqkvT, bf16_t* __restrict__ WoT) {
    __shared__ float tile[64][65];
    int bid = blockIdx.x;
    if (bid < 4096) {
        int i = (bid * 256 + threadIdx.x) * 4;
        float4 v = *(const float4*)(x + i);
        xb[i + 0] = f2bf(v.x);
        xb[i + 1] = f2bf(v.y);
        xb[i + 2] = f2bf(v.z);
        xb[i + 3] = f2bf(v.w);
        return;
    }
    int b2 = bid - 4096;
    int k0 = (b2 & 15) * 64;
    int n0 = (b2 >> 4) * 64;
    const float* W; bf16_t* WT; int np, nw;
    if (n0 < 3072) {
        W = (n0 < 1024) ? Wq : (n0 < 2048) ? Wk : Wv;
        np = n0 & 1023; WT = WqkvT; nw = n0;
    } else {
        W = Wo; np = n0 - 3072; WT = WoT; nw = n0 - 3072;
    }
    int tx = threadIdx.x & 63, ty = threadIdx.x >> 6;
    #pragma unroll
    for (int r = ty; r < 64; r += 4)
        tile[r][tx] = W[(size_t)(k0 + r) * 1024 + np + tx];
    __syncthreads();
    #pragma unroll
    for (int r = ty; r < 64; r += 4)
        WT[(size_t)(nw + r) * 1024 + k0 + tx] = f2bf(tile[tx][r]);
}

// ---------- QKV GEMM v3: BKK=32 dbuf, stage-before-compute, FIXED swizzle key ----------
// R8: R7's structure was right but its swizzle key (r&3) caused 4-way LDS read
// conflicts (65K -> 3.2M SQ_LDS_BANK_CONFLICT): with 64B rows (16 dwords), rows
// alternate bank-halves, and among the 8 even rows of a fragment, r&3 takes only
// {0,2} -> 8 rows on 2 chunk-slots. Key (r>>1)&3 cycles 0..3 within each parity
// class -> 2 rows/slot per 16-lane phase = 2-way = free (m136). Key depends only
// on l15 (row = 16m + l15), so the read-side XOR is lane-static.
#define BM 128
#define BN 128

__global__ __launch_bounds__(256) void k_gemm_qkv(
    const bf16_t* __restrict__ A, const bf16_t* __restrict__ BT, int K,
    const float* __restrict__ bias0, const float* __restrict__ bias1,
    const float* __restrict__ bias2,
    bf16_t* __restrict__ outQ, bf16_t* __restrict__ outK, bf16_t* __restrict__ outVt) {
    // 4 x [128][32] bf16 = 32KB; epilogue overlays the same 32KB as Ct[128][128]
    __shared__ __align__(16) bf16_t smem[4 * 128 * 32];
    bf16_t* const As0 = smem;
    bf16_t* const As1 = smem + 128 * 32;
    bf16_t* const Bs0 = smem + 2 * 128 * 32;
    bf16_t* const Bs1 = smem + 3 * 128 * 32;
    int m0 = blockIdx.x * BM;
    int n0 = blockIdx.y * BN;
    int t = threadIdx.x;
    int wid = t >> 6, lane = t & 63, l15 = lane & 15, quad = lane >> 4;
    int wr = (wid >> 1) * 64, wc = (wid & 1) * 64;
    // staging constants for [128][32] tiles: 2 calls/thread/matrix
    int sr = t >> 2;                     // row 0..63 (+64 second call)
    int sc = (t & 3) ^ ((sr >> 1) & 3);  // XOR-swizzled source chunk (key (r>>1)&3)
    int sl = (t & 3) * 8;                // linear dst chunk
    const f32x4 fzero = {0.f, 0.f, 0.f, 0.f};
    f32x4 acc[4][4];
    #pragma unroll
    for (int i = 0; i < 4; i++)
        #pragma unroll
        for (int j = 0; j < 4; j++) acc[i][j] = fzero;

    int secb = n0 >> 10;  // block-uniform: 0=Q, 1=K, 2=V
    int colA = (quad ^ ((l15 >> 1) & 3)) << 3;  // lane's k-chunk at XOR'd physical slot

    auto STAGE = [&](bf16_t* __restrict__ Ad, bf16_t* __restrict__ Bd, int k0) {
        #pragma unroll
        for (int p = 0; p < 2; p++) {
            int r = p * 64 + sr;
            gld_lds16(&A[(size_t)(m0 + r) * K + k0 + sc * 8], &Ad[r * 32 + sl]);
            gld_lds16(&BT[(size_t)(n0 + r) * K + k0 + sc * 8], &Bd[r * 32 + sl]);
        }
    };

    auto STEP = [&](const bf16_t* __restrict__ Ar, const bf16_t* __restrict__ Br,
                    bf16_t* __restrict__ Aw, bf16_t* __restrict__ Bw, int i) {
        if (i + 1 < 32) STAGE(Aw, Bw, (i + 1) * 32);
        bf16x8 af[4], bfr[4];
        #pragma unroll
        for (int mt = 0; mt < 4; mt++)
            af[mt] = *(const bf16x8*)&Ar[(wr + mt * 16 + l15) * 32 + colA];
        #pragma unroll
        for (int nt = 0; nt < 4; nt++)
            bfr[nt] = *(const bf16x8*)&Br[(wc + nt * 16 + l15) * 32 + colA];
        __builtin_amdgcn_s_setprio(1);
        if (secb == 2) {
            #pragma unroll
            for (int mt = 0; mt < 4; mt++)
                #pragma unroll
                for (int nt = 0; nt < 4; nt++)
                    acc[mt][nt] = __builtin_amdgcn_mfma_f32_16x16x32_bf16(
                        af[mt], bfr[nt], acc[mt][nt], 0, 0, 0);
        } else {
            #pragma unroll
            for (int i2 = 0; i2 < 4; i2++)
                #pragma unroll
                for (int j = 0; j < 4; j++)
                    acc[i2][j] = __builtin_amdgcn_mfma_f32_16x16x32_bf16(
                        bfr[i2], af[j], acc[i2][j], 0, 0, 0);
        }
        __builtin_amdgcn_s_setprio(0);
        if (i + 1 < 32) __syncthreads();
    };

    STAGE(As0, Bs0, 0);
    __syncthreads();
    for (int i = 0; i < 32; i += 2) {
        STEP(As0, Bs0, As1, Bs1, i);
        STEP(As1, Bs1, As0, Bs0, i + 1);
    }

    if (secb == 2) {
        __syncthreads();          // all waves done with As/Bs before overlay
        bf16_t* const Ct = smem;  // 128*128*2B = 32KB overlay
        int nbase = n0 & 1023;
        #pragma unroll
        for (int mt = 0; mt < 4; mt++) {
            #pragma unroll
            for (int nt = 0; nt < 4; nt++) {
                int dl = wc + nt * 16 + l15;
                float bv = bias2[nbase + dl];
                int sl2 = wr + mt * 16 + quad * 4;  // multiple of 4
                uint2 pk;
                pk.x = pack2t(acc[mt][nt][0] + bv, acc[mt][nt][1] + bv);
                pk.y = pack2t(acc[mt][nt][2] + bv, acc[mt][nt][3] + bv);
                int c4 = (sl2 >> 2) ^ ((dl & 7) << 1);
                *(uint2*)&Ct[dl * 128 + c4 * 4] = pk;
            }
        }
        __syncthreads();
        int b = m0 >> 11, sb = m0 & 2047;
        #pragma unroll
        for (int rr = 0; rr < 8; rr++) {
            int row = rr * 16 + (t >> 4);      // d-local 0..127
            int s8 = t & 15;                   // 16B chunk along s
            int c4 = (s8 * 2) ^ ((row & 7) << 1);
            uint4 vv = *(const uint4*)&Ct[row * 128 + c4 * 4];
            int nn = nbase + row;
            int h = nn >> 6, d = nn & 63;
            *(uint4*)&outVt[(((size_t)(b * NH + h)) * DKV + d) * S_LEN + sb + s8 * 8] = vv;
        }
        return;
    }

    {
        const float* bias = (secb == 0) ? bias0 : bias1;
        bf16_t* outP = (secb == 0) ? outQ : outK;
        float scale = (secb == 0) ? QSCALE : 1.0f;
        #pragma unroll
        for (int i = 0; i < 4; i++) {
            #pragma unroll
            for (int j = 0; j < 4; j++) {
                int nn = (n0 + wc + i * 16 + quad * 4) & 1023;  // multiple of 4
                float4 bv = *(const float4*)&bias[nn];
                int gr = m0 + wr + j * 16 + l15;
                int b = gr >> 11, s = gr & 2047;
                int h = nn >> 6, d0 = nn & 63;
                float v0 = (acc[i][j][0] + bv.x) * scale;
                float v1 = (acc[i][j][1] + bv.y) * scale;
                float v2 = (acc[i][j][2] + bv.z) * scale;
                float v3 = (acc[i][j][3] + bv.w) * scale;
                uint2 pk;
                pk.x = pack2r(v0, v1);
                pk.y = pack2r(v2, v3);
                *(uint2*)&outP[(((size_t)(b * NH + h)) * S_LEN + s) * DKV + d0] = pk;
            }
        }
    }
}

// ---------- out GEMM (verified R5): swapped operands -> float4 stores ----------
__global__ __launch_bounds__(256) void k_gemm_out(
    const bf16_t* __restrict__ A, const bf16_t* __restrict__ BT, int N, int K,
    const float* __restrict__ bias, float* __restrict__ outF) {
    __shared__ __align__(16) bf16_t As[128 * 64];
    __shared__ __align__(16) bf16_t Bs[64 * 64];
    int m0 = blockIdx.x * 128;
    int n0 = blockIdx.y * 64;
    int t = threadIdx.x;
    int wid = t >> 6, lane = t & 63, l15 = lane & 15, quad = lane >> 4;
    int wr = wid * 32;
    int srow = t >> 3;
    int schunk = (t & 7) ^ (srow & 7);
    int sldst = (t & 7) * 8;
    const f32x4 fzero = {0.f, 0.f, 0.f, 0.f};
    f32x4 acc[4][2];  // [n-tile][m-tile] (swapped orientation)
    #pragma unroll
    for (int i = 0; i < 4; i++)
        #pragma unroll
        for (int j = 0; j < 2; j++) acc[i][j] = fzero;

    int r7 = l15 & 7;
    for (int k0 = 0; k0 < K; k0 += 64) {
        #pragma unroll
        for (int p = 0; p < 4; p++) {
            int r = p * 32 + srow;
            gld_lds16(&A[(size_t)(m0 + r) * K + k0 + schunk * 8], &As[r * 64 + sldst]);
        }
        #pragma unroll
        for (int p = 0; p < 2; p++) {
            int r = p * 32 + srow;
            gld_lds16(&BT[(size_t)(n0 + r) * K + k0 + schunk * 8], &Bs[r * 64 + sldst]);
        }
        __syncthreads();
        #pragma unroll
        for (int kk = 0; kk < 64; kk += 32) {
            int g = quad + (kk >> 3);
            int col = ((g ^ r7) << 3);
            bf16x8 af[2], bfr[4];
            #pragma unroll
            for (int j = 0; j < 2; j++)
                af[j] = *(const bf16x8*)&As[(wr + j * 16 + l15) * 64 + col];
            #pragma unroll
            for (int i = 0; i < 4; i++)
                bfr[i] = *(const bf16x8*)&Bs[(i * 16 + l15) * 64 + col];
            #pragma unroll
            for (int i = 0; i < 4; i++)
                #pragma unroll
                for (int j = 0; j < 2; j++)
                    acc[i][j] = __builtin_amdgcn_mfma_f32_16x16x32_bf16(
                        bfr[i], af[j], acc[i][j], 0, 0, 0);
        }
        __syncthreads();
    }

    #pragma unroll
    for (int i = 0; i < 4; i++) {
        #pragma unroll
        for (int j = 0; j < 2; j++) {
            int nc = n0 + i * 16 + quad * 4;   // multiple of 4
            float4 bv = *(const float4*)&bias[nc];
            int mr = m0 + wr + j * 16 + l15;
            float4 o;
            o.x = acc[i][j][0] + bv.x;
            o.y = acc[i][j][1] + bv.y;
            o.z = acc[i][j][2] + bv.z;
            o.w = acc[i][j][3] + bv.w;
            *(float4*)&outF[(size_t)mr * N + nc] = o;
        }
    }
}

// ---------- flash attention v11 (verified R4/R5/R7) ----------
// Double-buffered KV=64 tiles, STAGE(next) before compute(cur), one barrier per
// tile; pad-mask gated behind wave-uniform scan; Q direct from global; setprio(1)
// around MFMA clusters; native exp2. LDS 40KB -> 4 blocks/CU.
__global__ __launch_bounds__(256, 4) void k_attn11(
    const bf16_t* __restrict__ Q, const bf16_t* __restrict__ Kg,
    const bf16_t* __restrict__ Vt, const unsigned char* __restrict__ mask,
    bf16_t* __restrict__ O) {
    __shared__ __align__(16) bf16_t Ks0[64 * 64];
    __shared__ __align__(16) bf16_t Ks1[64 * 64];
    __shared__ __align__(16) bf16_t Vs0[64 * 64];
    __shared__ __align__(16) bf16_t Vs1[64 * 64];
    __shared__ __align__(16) bf16_t Ps[64 * 64];  // per-wave 16-row P buffer

    int bid = blockIdx.x;
    int bh = bid & 31;
    int u = bid >> 5;
    int a = u & 7, g2 = u >> 3;
    int qt = (g2 == 0) ? 31 - a : (g2 == 1) ? a : (g2 == 2) ? 23 - a : 8 + a;
    int b = bh >> 4, h = bh & 15;
    int t = threadIdx.x;
    int w = t >> 6, lane = t & 63, l15 = lane & 15, quad = lane >> 4;
    int r7 = l15 & 7;

    // wave-uniform: any padded position in this batch row?
    bool maskany;
    {
        const uint2* mrow = (const uint2*)&mask[b * S_LEN];
        uint2 m0 = mrow[lane], m1 = mrow[lane + 64];
        uint2 m2 = mrow[lane + 128], m3 = mrow[lane + 192];
        uint32_t mo = (m0.x | m0.y) | (m1.x | m1.y) | (m2.x | m2.y) | (m3.x | m3.y);
        maskany = __any(mo != 0);
    }

    // Q fragments straight from global (row = this lane's q, 2 x 16B chunks)
    const bf16_t* Qrow = Q + ((size_t)bh * S_LEN + qt * 64 + w * 16 + l15) * DKV;
    bf16x8 qf0 = *(const bf16x8*)&Qrow[quad * 8];
    bf16x8 qf1 = *(const bf16x8*)&Qrow[32 + quad * 8];

    const bf16_t* Kbh = Kg + (size_t)bh * S_LEN * DKV;   // [s][64]
    const bf16_t* Vbh = Vt + (size_t)bh * DKV * S_LEN;   // [64][2048]

    const f32x4 fzero = {0.f, 0.f, 0.f, 0.f};
    f32x4 oacc[4];
    f32x4 lacc = fzero;
    #pragma unroll
    for (int nt = 0; nt < 4; nt++) oacc[nt] = fzero;

    const bf16_t one_b = (bf16_t)1.0f;
    const bf16x8 onesf = {one_b, one_b, one_b, one_b, one_b, one_b, one_b, one_b};

    int qg = qt * 64 + w * 16 + l15;  // lane's q column in S^T
    int qmin = qt * 64 + w * 16;

    // staging lane constants ([64][64] tile, 8 chunks/row)
    int sr = t >> 3;
    int sc = (t & 7) ^ (sr & 7);
    int sl = (t & 7) * 8;

    // prologue: stage tile 0 into buffer 0
    #pragma unroll
    for (int p = 0; p < 2; p++) {
        int r = p * 32 + sr;
        gld_lds16(&Kbh[(size_t)r * DKV + sc * 8], &Ks0[r * 64 + sl]);
        gld_lds16(&Vbh[(size_t)r * S_LEN + sc * 8], &Vs0[r * 64 + sl]);
    }
    __syncthreads();

    auto TILE = [&](const bf16_t* __restrict__ Kr, const bf16_t* __restrict__ Vr,
                    bf16_t* __restrict__ Kw, bf16_t* __restrict__ Vw, int kt) {
        if (kt < qt) {
            int kb2 = (kt + 1) * 64;
            #pragma unroll
            for (int p = 0; p < 2; p++) {
                int r = p * 32 + sr;
                gld_lds16(&Kbh[(size_t)(kb2 + r) * DKV + sc * 8], &Kw[r * 64 + sl]);
                gld_lds16(&Vbh[(size_t)r * S_LEN + kb2 + sc * 8], &Vw[r * 64 + sl]);
            }
        }
        int kbase = kt * 64;

        // S^T subtile: row k = mt*16+quad*4+r, col q = l15
        f32x4 sacc[4];
        #pragma unroll
        for (int mt = 0; mt < 4; mt++) sacc[mt] = fzero;
        #pragma unroll
        for (int kk = 0; kk < 64; kk += 32) {
            bf16x8 qf = kk ? qf1 : qf0;
            int col = (((quad + (kk >> 3)) ^ r7) << 3);
            bf16x8 af[4];
            #pragma unroll
            for (int mt = 0; mt < 4; mt++)
                af[mt] = *(const bf16x8*)&Kr[(mt * 16 + l15) * 64 + col];
            __builtin_amdgcn_s_setprio(1);
            #pragma unroll
            for (int mt = 0; mt < 4; mt++)
                sacc[mt] = __builtin_amdgcn_mfma_f32_16x16x32_bf16(af[mt], qf, sacc[mt], 0, 0, 0);
            __builtin_amdgcn_s_setprio(0);
        }

        if (maskany) {  // rare path: apply pad mask from global bytes
            #pragma unroll
            for (int mt = 0; mt < 4; mt++) {
                uint32_t mb = *(const uint32_t*)&mask[b * S_LEN + kbase + mt * 16 + quad * 4];
                #pragma unroll
                for (int r = 0; r < 4; r++)
                    sacc[mt][r] += (float)((mb >> (8 * r)) & 0xffu) * -1e30f;
            }
        }
        if (kt == qt) {  // causal mask only on the diagonal tile
            #pragma unroll
            for (int mt = 0; mt < 4; mt++) {
                int kgb = kbase + mt * 16 + quad * 4;
                #pragma unroll
                for (int r = 0; r < 4; r++)
                    if (kgb + r > qg) sacc[mt][r] = -1e30f;
            }
        }
        // p = exp2(s)
        #pragma unroll
        for (int mt = 0; mt < 4; mt++) {
            uint2 pk;
            pk.x = pack2t(exp2_native(sacc[mt][0]), exp2_native(sacc[mt][1]));
            pk.y = pack2t(exp2_native(sacc[mt][2]), exp2_native(sacc[mt][3]));
            int pc = (mt * 2 + (quad >> 1)) ^ r7;
            *(uint2*)&Ps[(w * 16 + l15) * 64 + pc * 8 + (quad & 1) * 4] = pk;
        }

        // O += P V; l += P * ones
        #pragma unroll
        for (int kk = 0; kk < 64; kk += 32) {
            int vcol = (((quad + (kk >> 3)) ^ r7) << 3);
            bf16x8 pf = *(const bf16x8*)&Ps[(w * 16 + l15) * 64 + vcol];
            bf16x8 vf[4];
            #pragma unroll
            for (int nt = 0; nt < 4; nt++)
                vf[nt] = *(const bf16x8*)&Vr[(nt * 16 + l15) * 64 + vcol];
            __builtin_amdgcn_s_setprio(1);
            #pragma unroll
            for (int nt = 0; nt < 4; nt++)
                oacc[nt] = __builtin_amdgcn_mfma_f32_16x16x32_bf16(pf, vf[nt], oacc[nt], 0, 0, 0);
            lacc = __builtin_amdgcn_mfma_f32_16x16x32_bf16(pf, onesf, lacc, 0, 0, 0);
            __builtin_amdgcn_s_setprio(0);
        }

        if (kt < qt) __syncthreads();  // drains stage DMA; block-uniform condition
    };

    for (int kt = 0; kt <= qt; kt += 2) {
        TILE(Ks0, Vs0, Ks1, Vs1, kt);
        if (kt + 1 <= qt) TILE(Ks1, Vs1, Ks0, Vs0, kt + 1);
    }

    #pragma unroll
    for (int r = 0; r < 4; r++) {
        float l = lacc[r];
        float invl = l > 0.f ? 1.f / l : 0.f;
        int q = qt * 64 + w * 16 + quad * 4 + r;
        #pragma unroll
        for (int nt = 0; nt < 4; nt++) {
            int d = nt * 16 + l15;
            O[((size_t)b * S_LEN + q) * D_MODEL + h * DKV + d] = f2bf(oacc[nt][r] * invl);
        }
    }
}

extern "C" void kernel_launch(void* const* d_in, const int* in_sizes, int n_in,
                              void* d_out, int out_size, void* d_ws, size_t ws_size,
                              hipStream_t stream) {
    const float* x = (const float*)d_in[0];
    const unsigned char* mask = (const unsigned char*)d_in[1];
    const float* Wq = (const float*)d_in[2];
    const float* bq = (const float*)d_in[3];
    const float* Wk = (const float*)d_in[4];
    const float* bk = (const float*)d_in[5];
    const float* Wv = (const float*)d_in[6];
    const float* bv = (const float*)d_in[7];
    const float* Wo = (const float*)d_in[8];
    const float* bo = (const float*)d_in[9];
    float* out = (float*)d_out;

    char* ws = (char*)d_ws;
    const size_t MB = 1024 * 1024;
    // Max ws footprint: 48 MB.
    bf16_t* xb    = (bf16_t*)(ws + 0 * MB);   // 8 MB
    bf16_t* WqkvT = (bf16_t*)(ws + 8 * MB);   // 6 MB
    bf16_t* WoT   = (bf16_t*)(ws + 14 * MB);  // 2 MB
    bf16_t* Qb    = (bf16_t*)(ws + 16 * MB);  // 8 MB [bh][s][64], pre-scaled QSCALE
    bf16_t* Kb    = (bf16_t*)(ws + 24 * MB);  // 8 MB [bh][s][64]
    bf16_t* Vtb   = (bf16_t*)(ws + 32 * MB);  // 8 MB V^T [bh][64][2048]
    bf16_t* AOb   = (bf16_t*)(ws + 40 * MB);  // 8 MB attn out [4096,1024]

    k_prep<<<dim3(4096 + 1024), dim3(256), 0, stream>>>(
        x, xb, Wq, Wk, Wv, Wo, WqkvT, WoT);
    k_gemm_qkv<<<dim3(32, 24), dim3(256), 0, stream>>>(
        xb, WqkvT, 1024, bq, bk, bv, Qb, Kb, Vtb);
    k_attn11<<<dim3(1024), dim3(256), 0, stream>>>(Qb, Kb, Vtb, mask, AOb);
    k_gemm_out<<<dim3(32, 16), dim3(256), 0, stream>>>(
        AOb, WoT, 1024, 1024, bo, out);
}

// Round 10
// 173.817 us; speedup vs baseline: 1.1178x; 1.0155x over previous
//
#include <hip/hip_runtime.h>
#include <stdint.h>

typedef __bf16 bf16_t;
typedef __bf16 bf16x8 __attribute__((ext_vector_type(8)));
typedef float f32x4 __attribute__((ext_vector_type(4)));

#define S_LEN 2048
#define D_MODEL 1024
#define NH 16
#define DKV 64
#define BATCH 2

// 0.125 (1/sqrt(64)) * log2(e): Q pre-scale so softmax runs in exp2 domain.
#define QSCALE 0.1803368801111204f

__device__ __forceinline__ uint16_t f2bfu(float f) {
    union { float f; uint32_t u; } c; c.f = f;
    return (uint16_t)((c.u + 0x7fffu + ((c.u >> 16) & 1u)) >> 16);
}
__device__ __forceinline__ bf16_t f2bf(float f) {
    union { uint16_t s; bf16_t b; } o; o.s = f2bfu(f);
    return o.b;
}
// truncation pack via v_perm: result = (lo>>16) | (hi & 0xFFFF0000)
__device__ __forceinline__ uint32_t pack2t(float lo, float hi) {
    union { float f; uint32_t u; } a, b; a.f = lo; b.f = hi;
    return __builtin_amdgcn_perm(b.u, a.u, 0x07060302);
}
// rounding pack (RTNE, matches f2bf) — two bf16 in one u32
__device__ __forceinline__ uint32_t pack2r(float lo, float hi) {
    union { float f; uint32_t u; } a, b; a.f = lo; b.f = hi;
    uint32_t alo = a.u + 0x7fffu + ((a.u >> 16) & 1u);
    uint32_t bhi = b.u + 0x7fffu + ((b.u >> 16) & 1u);
    return __builtin_amdgcn_perm(bhi, alo, 0x07060302);
}
// native 2^x (trans pipe, 1 instr)
__device__ __forceinline__ float exp2_native(float x) {
    float r;
    asm("v_exp_f32 %0, %1" : "=v"(r) : "v"(x));
    return r;
}
// async global->LDS 16B DMA (dst = wave-uniform base + lane*16)
__device__ __forceinline__ void gld_lds16(const bf16_t* g, bf16_t* l) {
    __builtin_amdgcn_global_load_lds(
        (const __attribute__((address_space(1))) void*)g,
        (__attribute__((address_space(3))) void*)l, 16, 0, 0);
}

// ---------- merged prep: fp32->bf16 convert (x) + weight transpose, one launch ----------
__global__ __launch_bounds__(256) void k_prep(
    const float* __restrict__ x, bf16_t* __restrict__ xb,
    const float* __restrict__ Wq, const float* __restrict__ Wk,
    const float* __restrict__ Wv, const float* __restrict__ Wo,
    bf16_t* __restrict__ WqkvT, bf16_t* __restrict__ WoT) {
    __shared__ float tile[64][65];
    int bid = blockIdx.x;
    if (bid < 4096) {
        int i = (bid * 256 + threadIdx.x) * 4;
        float4 v = *(const float4*)(x + i);
        xb[i + 0] = f2bf(v.x);
        xb[i + 1] = f2bf(v.y);
        xb[i + 2] = f2bf(v.z);
        xb[i + 3] = f2bf(v.w);
        return;
    }
    int b2 = bid - 4096;
    int k0 = (b2 & 15) * 64;
    int n0 = (b2 >> 4) * 64;
    const float* W; bf16_t* WT; int np, nw;
    if (n0 < 3072) {
        W = (n0 < 1024) ? Wq : (n0 < 2048) ? Wk : Wv;
        np = n0 & 1023; WT = WqkvT; nw = n0;
    } else {
        W = Wo; np = n0 - 3072; WT = WoT; nw = n0 - 3072;
    }
    int tx = threadIdx.x & 63, ty = threadIdx.x >> 6;
    #pragma unroll
    for (int r = ty; r < 64; r += 4)
        tile[r][tx] = W[(size_t)(k0 + r) * 1024 + np + tx];
    __syncthreads();
    #pragma unroll
    for (int r = ty; r < 64; r += 4)
        WT[(size_t)(nw + r) * 1024 + k0 + tx] = f2bf(tile[tx][r]);
}

// ---------- QKV GEMM v3 (verified R8): BKK=32 dbuf, stage-before-compute ----------
// Swizzle key (r>>1)&3 -> 2-way LDS access = free (m136); R7's (r&3) was 4-way
// (3.2M conflicts). One barrier per 32-K step, prefetch issued a full compute
// phase ahead. Epilogues verified R5: Q/K swapped-operand stores, V LDS-transpose.
#define BM 128
#define BN 128

__global__ __launch_bounds__(256) void k_gemm_qkv(
    const bf16_t* __restrict__ A, const bf16_t* __restrict__ BT, int K,
    const float* __restrict__ bias0, const float* __restrict__ bias1,
    const float* __restrict__ bias2,
    bf16_t* __restrict__ outQ, bf16_t* __restrict__ outK, bf16_t* __restrict__ outVt) {
    // 4 x [128][32] bf16 = 32KB; epilogue overlays the same 32KB as Ct[128][128]
    __shared__ __align__(16) bf16_t smem[4 * 128 * 32];
    bf16_t* const As0 = smem;
    bf16_t* const As1 = smem + 128 * 32;
    bf16_t* const Bs0 = smem + 2 * 128 * 32;
    bf16_t* const Bs1 = smem + 3 * 128 * 32;
    int m0 = blockIdx.x * BM;
    int n0 = blockIdx.y * BN;
    int t = threadIdx.x;
    int wid = t >> 6, lane = t & 63, l15 = lane & 15, quad = lane >> 4;
    int wr = (wid >> 1) * 64, wc = (wid & 1) * 64;
    // staging constants for [128][32] tiles: 2 calls/thread/matrix
    int sr = t >> 2;                     // row 0..63 (+64 second call)
    int sc = (t & 3) ^ ((sr >> 1) & 3);  // XOR-swizzled source chunk (key (r>>1)&3)
    int sl = (t & 3) * 8;                // linear dst chunk
    const f32x4 fzero = {0.f, 0.f, 0.f, 0.f};
    f32x4 acc[4][4];
    #pragma unroll
    for (int i = 0; i < 4; i++)
        #pragma unroll
        for (int j = 0; j < 4; j++) acc[i][j] = fzero;

    int secb = n0 >> 10;  // block-uniform: 0=Q, 1=K, 2=V
    int colA = (quad ^ ((l15 >> 1) & 3)) << 3;  // lane's k-chunk at XOR'd physical slot

    auto STAGE = [&](bf16_t* __restrict__ Ad, bf16_t* __restrict__ Bd, int k0) {
        #pragma unroll
        for (int p = 0; p < 2; p++) {
            int r = p * 64 + sr;
            gld_lds16(&A[(size_t)(m0 + r) * K + k0 + sc * 8], &Ad[r * 32 + sl]);
            gld_lds16(&BT[(size_t)(n0 + r) * K + k0 + sc * 8], &Bd[r * 32 + sl]);
        }
    };

    auto STEP = [&](const bf16_t* __restrict__ Ar, const bf16_t* __restrict__ Br,
                    bf16_t* __restrict__ Aw, bf16_t* __restrict__ Bw, int i) {
        if (i + 1 < 32) STAGE(Aw, Bw, (i + 1) * 32);
        bf16x8 af[4], bfr[4];
        #pragma unroll
        for (int mt = 0; mt < 4; mt++)
            af[mt] = *(const bf16x8*)&Ar[(wr + mt * 16 + l15) * 32 + colA];
        #pragma unroll
        for (int nt = 0; nt < 4; nt++)
            bfr[nt] = *(const bf16x8*)&Br[(wc + nt * 16 + l15) * 32 + colA];
        __builtin_amdgcn_s_setprio(1);
        if (secb == 2) {
            #pragma unroll
            for (int mt = 0; mt < 4; mt++)
                #pragma unroll
                for (int nt = 0; nt < 4; nt++)
                    acc[mt][nt] = __builtin_amdgcn_mfma_f32_16x16x32_bf16(
                        af[mt], bfr[nt], acc[mt][nt], 0, 0, 0);
        } else {
            #pragma unroll
            for (int i2 = 0; i2 < 4; i2++)
                #pragma unroll
                for (int j = 0; j < 4; j++)
                    acc[i2][j] = __builtin_amdgcn_mfma_f32_16x16x32_bf16(
                        bfr[i2], af[j], acc[i2][j], 0, 0, 0);
        }
        __builtin_amdgcn_s_setprio(0);
        if (i + 1 < 32) __syncthreads();
    };

    STAGE(As0, Bs0, 0);
    __syncthreads();
    for (int i = 0; i < 32; i += 2) {
        STEP(As0, Bs0, As1, Bs1, i);
        STEP(As1, Bs1, As0, Bs0, i + 1);
    }

    if (secb == 2) {
        __syncthreads();          // all waves done with As/Bs before overlay
        bf16_t* const Ct = smem;  // 128*128*2B = 32KB overlay
        int nbase = n0 & 1023;
        #pragma unroll
        for (int mt = 0; mt < 4; mt++) {
            #pragma unroll
            for (int nt = 0; nt < 4; nt++) {
                int dl = wc + nt * 16 + l15;
                float bv = bias2[nbase + dl];
                int sl2 = wr + mt * 16 + quad * 4;  // multiple of 4
                uint2 pk;
                pk.x = pack2t(acc[mt][nt][0] + bv, acc[mt][nt][1] + bv);
                pk.y = pack2t(acc[mt][nt][2] + bv, acc[mt][nt][3] + bv);
                int c4 = (sl2 >> 2) ^ ((dl & 7) << 1);
                *(uint2*)&Ct[dl * 128 + c4 * 4] = pk;
            }
        }
        __syncthreads();
        int b = m0 >> 11, sb = m0 & 2047;
        #pragma unroll
        for (int rr = 0; rr < 8; rr++) {
            int row = rr * 16 + (t >> 4);      // d-local 0..127
            int s8 = t & 15;                   // 16B chunk along s
            int c4 = (s8 * 2) ^ ((row & 7) << 1);
            uint4 vv = *(const uint4*)&Ct[row * 128 + c4 * 4];
            int nn = nbase + row;
            int h = nn >> 6, d = nn & 63;
            *(uint4*)&outVt[(((size_t)(b * NH + h)) * DKV + d) * S_LEN + sb + s8 * 8] = vv;
        }
        return;
    }

    {
        const float* bias = (secb == 0) ? bias0 : bias1;
        bf16_t* outP = (secb == 0) ? outQ : outK;
        float scale = (secb == 0) ? QSCALE : 1.0f;
        #pragma unroll
        for (int i = 0; i < 4; i++) {
            #pragma unroll
            for (int j = 0; j < 4; j++) {
                int nn = (n0 + wc + i * 16 + quad * 4) & 1023;  // multiple of 4
                float4 bv = *(const float4*)&bias[nn];
                int gr = m0 + wr + j * 16 + l15;
                int b = gr >> 11, s = gr & 2047;
                int h = nn >> 6, d0 = nn & 63;
                float v0 = (acc[i][j][0] + bv.x) * scale;
                float v1 = (acc[i][j][1] + bv.y) * scale;
                float v2 = (acc[i][j][2] + bv.z) * scale;
                float v3 = (acc[i][j][3] + bv.w) * scale;
                uint2 pk;
                pk.x = pack2r(v0, v1);
                pk.y = pack2r(v2, v3);
                *(uint2*)&outP[(((size_t)(b * NH + h)) * S_LEN + s) * DKV + d0] = pk;
            }
        }
    }
}

// ---------- out GEMM v2 (R9): BKK=32 dbuf, stage-before-compute, free swizzle ----------
// Port of the twice-verified v3 recipe (attn v10, gemm_qkv R8). 2x[128][32] A +
// 2x[64][32] B = 24KB LDS. 3 gld_lds/thread/stage; one barrier per 32-K step with
// the prefetch issued a full compute phase (6 ds_read_b128 + 8 MFMA) ahead.
// Epilogue verified R5: swapped-operand float4 stores (64B runs).
__global__ __launch_bounds__(256) void k_gemm_out(
    const bf16_t* __restrict__ A, const bf16_t* __restrict__ BT, int N, int K,
    const float* __restrict__ bias, float* __restrict__ outF) {
    __shared__ __align__(16) bf16_t As0[128 * 32];
    __shared__ __align__(16) bf16_t As1[128 * 32];
    __shared__ __align__(16) bf16_t Bs0[64 * 32];
    __shared__ __align__(16) bf16_t Bs1[64 * 32];
    int m0 = blockIdx.x * 128;
    int n0 = blockIdx.y * 64;
    int t = threadIdx.x;
    int wid = t >> 6, lane = t & 63, l15 = lane & 15, quad = lane >> 4;
    int wr = wid * 32;
    int sr = t >> 2;                     // row 0..63
    int sc = (t & 3) ^ ((sr >> 1) & 3);  // XOR-swizzled source chunk
    int sl = (t & 3) * 8;                // linear dst chunk
    const f32x4 fzero = {0.f, 0.f, 0.f, 0.f};
    f32x4 acc[4][2];  // [n-tile][m-tile] (swapped orientation)
    #pragma unroll
    for (int i = 0; i < 4; i++)
        #pragma unroll
        for (int j = 0; j < 2; j++) acc[i][j] = fzero;

    int colA = (quad ^ ((l15 >> 1) & 3)) << 3;

    auto STAGE = [&](bf16_t* __restrict__ Ad, bf16_t* __restrict__ Bd, int k0) {
        #pragma unroll
        for (int p = 0; p < 2; p++) {
            int r = p * 64 + sr;
            gld_lds16(&A[(size_t)(m0 + r) * K + k0 + sc * 8], &Ad[r * 32 + sl]);
        }
        gld_lds16(&BT[(size_t)(n0 + sr) * K + k0 + sc * 8], &Bd[sr * 32 + sl]);
    };

    auto STEP = [&](const bf16_t* __restrict__ Ar, const bf16_t* __restrict__ Br,
                    bf16_t* __restrict__ Aw, bf16_t* __restrict__ Bw, int i) {
        if (i + 1 < 32) STAGE(Aw, Bw, (i + 1) * 32);
        bf16x8 af[2], bfr[4];
        #pragma unroll
        for (int j = 0; j < 2; j++)
            af[j] = *(const bf16x8*)&Ar[(wr + j * 16 + l15) * 32 + colA];
        #pragma unroll
        for (int i2 = 0; i2 < 4; i2++)
            bfr[i2] = *(const bf16x8*)&Br[(i2 * 16 + l15) * 32 + colA];
        __builtin_amdgcn_s_setprio(1);
        #pragma unroll
        for (int i2 = 0; i2 < 4; i2++)
            #pragma unroll
            for (int j = 0; j < 2; j++)
                acc[i2][j] = __builtin_amdgcn_mfma_f32_16x16x32_bf16(
                    bfr[i2], af[j], acc[i2][j], 0, 0, 0);
        __builtin_amdgcn_s_setprio(0);
        if (i + 1 < 32) __syncthreads();
    };

    STAGE(As0, Bs0, 0);
    __syncthreads();
    for (int i = 0; i < 32; i += 2) {
        STEP(As0, Bs0, As1, Bs1, i);
        STEP(As1, Bs1, As0, Bs0, i + 1);
    }

    // C'[n][m]: lane holds 4 consecutive n at fixed m -> float4 stores (64B runs)
    #pragma unroll
    for (int i = 0; i < 4; i++) {
        #pragma unroll
        for (int j = 0; j < 2; j++) {
            int nc = n0 + i * 16 + quad * 4;   // multiple of 4
            float4 bv = *(const float4*)&bias[nc];
            int mr = m0 + wr + j * 16 + l15;
            float4 o;
            o.x = acc[i][j][0] + bv.x;
            o.y = acc[i][j][1] + bv.y;
            o.z = acc[i][j][2] + bv.z;
            o.w = acc[i][j][3] + bv.w;
            *(float4*)&outF[(size_t)mr * N + nc] = o;
        }
    }
}

// ---------- flash attention v11 (verified R4/R5/R7/R8) ----------
// Double-buffered KV=64 tiles, STAGE(next) before compute(cur), one barrier per
// tile; pad-mask gated behind wave-uniform scan; Q direct from global; setprio(1)
// around MFMA clusters; native exp2. LDS 40KB -> 4 blocks/CU.
__global__ __launch_bounds__(256, 4) void k_attn11(
    const bf16_t* __restrict__ Q, const bf16_t* __restrict__ Kg,
    const bf16_t* __restrict__ Vt, const unsigned char* __restrict__ mask,
    bf16_t* __restrict__ O) {
    __shared__ __align__(16) bf16_t Ks0[64 * 64];
    __shared__ __align__(16) bf16_t Ks1[64 * 64];
    __shared__ __align__(16) bf16_t Vs0[64 * 64];
    __shared__ __align__(16) bf16_t Vs1[64 * 64];
    __shared__ __align__(16) bf16_t Ps[64 * 64];  // per-wave 16-row P buffer

    int bid = blockIdx.x;
    int bh = bid & 31;
    int u = bid >> 5;
    int a = u & 7, g2 = u >> 3;
    int qt = (g2 == 0) ? 31 - a : (g2 == 1) ? a : (g2 == 2) ? 23 - a : 8 + a;
    int b = bh >> 4, h = bh & 15;
    int t = threadIdx.x;
    int w = t >> 6, lane = t & 63, l15 = lane & 15, quad = lane >> 4;
    int r7 = l15 & 7;

    // wave-uniform: any padded position in this batch row?
    bool maskany;
    {
        const uint2* mrow = (const uint2*)&mask[b * S_LEN];
        uint2 m0 = mrow[lane], m1 = mrow[lane + 64];
        uint2 m2 = mrow[lane + 128], m3 = mrow[lane + 192];
        uint32_t mo = (m0.x | m0.y) | (m1.x | m1.y) | (m2.x | m2.y) | (m3.x | m3.y);
        maskany = __any(mo != 0);
    }

    // Q fragments straight from global (row = this lane's q, 2 x 16B chunks)
    const bf16_t* Qrow = Q + ((size_t)bh * S_LEN + qt * 64 + w * 16 + l15) * DKV;
    bf16x8 qf0 = *(const bf16x8*)&Qrow[quad * 8];
    bf16x8 qf1 = *(const bf16x8*)&Qrow[32 + quad * 8];

    const bf16_t* Kbh = Kg + (size_t)bh * S_LEN * DKV;   // [s][64]
    const bf16_t* Vbh = Vt + (size_t)bh * DKV * S_LEN;   // [64][2048]

    const f32x4 fzero = {0.f, 0.f, 0.f, 0.f};
    f32x4 oacc[4];
    f32x4 lacc = fzero;
    #pragma unroll
    for (int nt = 0; nt < 4; nt++) oacc[nt] = fzero;

    const bf16_t one_b = (bf16_t)1.0f;
    const bf16x8 onesf = {one_b, one_b, one_b, one_b, one_b, one_b, one_b, one_b};

    int qg = qt * 64 + w * 16 + l15;  // lane's q column in S^T
    int qmin = qt * 64 + w * 16;

    // staging lane constants ([64][64] tile, 8 chunks/row)
    int sr = t >> 3;
    int sc = (t & 7) ^ (sr & 7);
    int sl = (t & 7) * 8;

    // prologue: stage tile 0 into buffer 0
    #pragma unroll
    for (int p = 0; p < 2; p++) {
        int r = p * 32 + sr;
        gld_lds16(&Kbh[(size_t)r * DKV + sc * 8], &Ks0[r * 64 + sl]);
        gld_lds16(&Vbh[(size_t)r * S_LEN + sc * 8], &Vs0[r * 64 + sl]);
    }
    __syncthreads();

    auto TILE = [&](const bf16_t* __restrict__ Kr, const bf16_t* __restrict__ Vr,
                    bf16_t* __restrict__ Kw, bf16_t* __restrict__ Vw, int kt) {
        if (kt < qt) {
            int kb2 = (kt + 1) * 64;
            #pragma unroll
            for (int p = 0; p < 2; p++) {
                int r = p * 32 + sr;
                gld_lds16(&Kbh[(size_t)(kb2 + r) * DKV + sc * 8], &Kw[r * 64 + sl]);
                gld_lds16(&Vbh[(size_t)r * S_LEN + kb2 + sc * 8], &Vw[r * 64 + sl]);
            }
        }
        int kbase = kt * 64;

        // S^T subtile: row k = mt*16+quad*4+r, col q = l15
        f32x4 sacc[4];
        #pragma unroll
        for (int mt = 0; mt < 4; mt++) sacc[mt] = fzero;
        #pragma unroll
        for (int kk = 0; kk < 64; kk += 32) {
            bf16x8 qf = kk ? qf1 : qf0;
            int col = (((quad + (kk >> 3)) ^ r7) << 3);
            bf16x8 af[4];
            #pragma unroll
            for (int mt = 0; mt < 4; mt++)
                af[mt] = *(const bf16x8*)&Kr[(mt * 16 + l15) * 64 + col];
            __builtin_amdgcn_s_setprio(1);
            #pragma unroll
            for (int mt = 0; mt < 4; mt++)
                sacc[mt] = __builtin_amdgcn_mfma_f32_16x16x32_bf16(af[mt], qf, sacc[mt], 0, 0, 0);
            __builtin_amdgcn_s_setprio(0);
        }

        if (maskany) {  // rare path: apply pad mask from global bytes
            #pragma unroll
            for (int mt = 0; mt < 4; mt++) {
                uint32_t mb = *(const uint32_t*)&mask[b * S_LEN + kbase + mt * 16 + quad * 4];
                #pragma unroll
                for (int r = 0; r < 4; r++)
                    sacc[mt][r] += (float)((mb >> (8 * r)) & 0xffu) * -1e30f;
            }
        }
        if (kt == qt) {  // causal mask only on the diagonal tile
            #pragma unroll
            for (int mt = 0; mt < 4; mt++) {
                int kgb = kbase + mt * 16 + quad * 4;
                #pragma unroll
                for (int r = 0; r < 4; r++)
                    if (kgb + r > qg) sacc[mt][r] = -1e30f;
            }
        }
        // p = exp2(s)
        #pragma unroll
        for (int mt = 0; mt < 4; mt++) {
            uint2 pk;
            pk.x = pack2t(exp2_native(sacc[mt][0]), exp2_native(sacc[mt][1]));
            pk.y = pack2t(exp2_native(sacc[mt][2]), exp2_native(sacc[mt][3]));
            int pc = (mt * 2 + (quad >> 1)) ^ r7;
            *(uint2*)&Ps[(w * 16 + l15) * 64 + pc * 8 + (quad & 1) * 4] = pk;
        }

        // O += P V; l += P * ones
        #pragma unroll
        for (int kk = 0; kk < 64; kk += 32) {
            int vcol = (((quad + (kk >> 3)) ^ r7) << 3);
            bf16x8 pf = *(const bf16x8*)&Ps[(w * 16 + l15) * 64 + vcol];
            bf16x8 vf[4];
            #pragma unroll
            for (int nt = 0; nt < 4; nt++)
                vf[nt] = *(const bf16x8*)&Vr[(nt * 16 + l15) * 64 + vcol];
            __builtin_amdgcn_s_setprio(1);
            #pragma unroll
            for (int nt = 0; nt < 4; nt++)
                oacc[nt] = __builtin_amdgcn_mfma_f32_16x16x32_bf16(pf, vf[nt], oacc[nt], 0, 0, 0);
            lacc = __builtin_amdgcn_mfma_f32_16x16x32_bf16(pf, onesf, lacc, 0, 0, 0);
            __builtin_amdgcn_s_setprio(0);
        }

        if (kt < qt) __syncthreads();  // drains stage DMA; block-uniform condition
    };

    for (int kt = 0; kt <= qt; kt += 2) {
        TILE(Ks0, Vs0, Ks1, Vs1, kt);
        if (kt + 1 <= qt) TILE(Ks1, Vs1, Ks0, Vs0, kt + 1);
    }

    #pragma unroll
    for (int r = 0; r < 4; r++) {
        float l = lacc[r];
        float invl = l > 0.f ? 1.f / l : 0.f;
        int q = qt * 64 + w * 16 + quad * 4 + r;
        #pragma unroll
        for (int nt = 0; nt < 4; nt++) {
            int d = nt * 16 + l15;
            O[((size_t)b * S_LEN + q) * D_MODEL + h * DKV + d] = f2bf(oacc[nt][r] * invl);
        }
    }
}

extern "C" void kernel_launch(void* const* d_in, const int* in_sizes, int n_in,
                              void* d_out, int out_size, void* d_ws, size_t ws_size,
                              hipStream_t stream) {
    const float* x = (const float*)d_in[0];
    const unsigned char* mask = (const unsigned char*)d_in[1];
    const float* Wq = (const float*)d_in[2];
    const float* bq = (const float*)d_in[3];
    const float* Wk = (const float*)d_in[4];
    const float* bk = (const float*)d_in[5];
    const float* Wv = (const float*)d_in[6];
    const float* bv = (const float*)d_in[7];
    const float* Wo = (const float*)d_in[8];
    const float* bo = (const float*)d_in[9];
    float* out = (float*)d_out;

    char* ws = (char*)d_ws;
    const size_t MB = 1024 * 1024;
    // Max ws footprint: 48 MB.
    bf16_t* xb    = (bf16_t*)(ws + 0 * MB);   // 8 MB
    bf16_t* WqkvT = (bf16_t*)(ws + 8 * MB);   // 6 MB
    bf16_t* WoT   = (bf16_t*)(ws + 14 * MB);  // 2 MB
    bf16_t* Qb    = (bf16_t*)(ws + 16 * MB);  // 8 MB [bh][s][64], pre-scaled QSCALE
    bf16_t* Kb    = (bf16_t*)(ws + 24 * MB);  // 8 MB [bh][s][64]
    bf16_t* Vtb   = (bf16_t*)(ws + 32 * MB);  // 8 MB V^T [bh][64][2048]
    bf16_t* AOb   = (bf16_t*)(ws + 40 * MB);  // 8 MB attn out [4096,1024]

    k_prep<<<dim3(4096 + 1024), dim3(256), 0, stream>>>(
        x, xb, Wq, Wk, Wv, Wo, WqkvT, WoT);
    k_gemm_qkv<<<dim3(32, 24), dim3(256), 0, stream>>>(
        xb, WqkvT, 1024, bq, bk, bv, Qb, Kb, Vtb);
    k_attn11<<<dim3(1024), dim3(256), 0, stream>>>(Qb, Kb, Vtb, mask, AOb);
    k_gemm_out<<<dim3(32, 16), dim3(256), 0, stream>>>(
        AOb, WoT, 1024, 1024, bo, out);
}